// Round 5
// baseline (166.431 us; speedup 1.0000x reference)
//
#include <hip/hip_runtime.h>
#include <stdint.h>

// CtxAttention: additive attention (Bahdanau).
//   e[n,t]  = sum_a w_v[a] * tanh( enc_pad[n,t,:]·W_enc[a,:] + b_enc[a] + dec_prev[n,:]·W_dec[a,:] )
//   ali     = softmax_t(mask(e));  ctx[n,:] = sum_t ali[n,t] * enc_pad[n,t,:]
// Round-5 structure: NO bulk pre-convert of enc (round-3/4 showed that kernel stuck at
// 1.6 TB/s latency-bound, 88 us). k_score256 reg-stages A (enc fp32 -> cvt f16 ->
// swizzled ds_write) hidden under MFMA; B comes from a 1 MB pre-swizzled fp16 W16
// (k_wconvert, one 32B->16B convert per thread). ctx reads enc fp32 directly.

#define NB  32
#define TI  2000
#define ED  512
#define AD  512
#define M_TOT (NB * TI)          // 64000
#define NSPLIT 40
#define TCHUNK (TI / NSPLIT)     // 50
#define MT2 250                  // 256-row m-tiles (score granularity)
#define KT  8                    // k-tiles of 64
#define TILE_BYTES  16384        // 128 rows x 64 halves x 2B
#define TILE_HALVES 8192

using f16x8 = __attribute__((ext_vector_type(8))) _Float16;
using f32x4 = __attribute__((ext_vector_type(4))) float;

// swizzle within a 128x64-half tile; row r (0..127), byte-col c (16B aligned, 0..127)
__device__ __forceinline__ int swz(int r, int c) { return (r * 128 + c) ^ ((r & 7) << 4); }

#define GLD16(g, l)                                                     \
    __builtin_amdgcn_global_load_lds(                                   \
        (const __attribute__((address_space(1))) void*)(g),             \
        (__attribute__((address_space(3))) void*)(l), 16, 0, 0)

__device__ __forceinline__ float fast_tanh(float s) {
    s = fminf(fmaxf(s, -15.f), 15.f);
    float t = __expf(2.f * s);
    return __fdividef(t - 1.f, t + 1.f);
}

__device__ __forceinline__ f16x8 cvt8(float4 a, float4 b) {
    f16x8 h;
    h[0] = (_Float16)a.x; h[1] = (_Float16)a.y; h[2] = (_Float16)a.z; h[3] = (_Float16)a.w;
    h[4] = (_Float16)b.x; h[5] = (_Float16)b.y; h[6] = (_Float16)b.z; h[7] = (_Float16)b.w;
    return h;
}

// ---------------- Kernel 0: W_enc -> tiled swizzled fp16 (1 MB); + fused decdb ----------------
// bx in [0,128): convert blocks, one f16x8 store per thread; [128,160): decdb row n = bx-128.
__global__ void k_wconvert(const float* __restrict__ Wenc, _Float16* __restrict__ W16,
                           const float* __restrict__ dec_prev, const float* __restrict__ W_dec,
                           const float* __restrict__ b_enc, float* __restrict__ db) {
    __shared__ float xd[ED];
    int bx = blockIdx.x;
    int tid = threadIdx.x;
    if (bx >= 128) {
        // ---- decdb: db[n][a] = dec_prev[n,:]·W_dec[a,:] + b_enc[a] ----
        int n = bx - 128;
        for (int k = tid; k < ED; k += 256) xd[k] = dec_prev[n * ED + k];
        __syncthreads();
        for (int a = tid; a < AD; a += 256) {
            const float* wr = W_dec + (size_t)a * ED;
            float s = 0.f;
#pragma unroll 8
            for (int k = 0; k < ED; k += 4) {
                float4 w = *(const float4*)(wr + k);
                s += xd[k] * w.x + xd[k + 1] * w.y + xd[k + 2] * w.z + xd[k + 3] * w.w;
            }
            db[n * AD + a] = s + b_enc[a];
        }
        return;
    }
    int idx = bx * 4096 + tid * 16;    // byte offset into W16 (512 KB total)
    int wt  = idx >> 14;               // tile 0..31 (at = wt>>3, kt = wt&7)
    int o   = idx & 16383;
    int r   = o >> 7;                  // row 0..127
    int c2  = o & 127;                 // byte col
    int at  = wt >> 3, kt = wt & 7;
    const float* s = Wenc + ((size_t)(at * 128 + r)) * ED + kt * 64 + (c2 >> 1);
    float4 a = *(const float4*)s;
    float4 b = *(const float4*)(s + 4);
    *(f16x8*)((char*)W16 + (wt << 14) + swz(r, c2)) = cvt8(a, b);
}

// ---------------- Kernel 2: fused score GEMM, 256x256 tile, 8 waves, reg-staged A ----------------
// grid 512: fid -> g=fid>>4, r=fid&15, at2=r>>3, mt2=g*8+(r&7) (XCD-grouped).
__launch_bounds__(512, 2)
__global__ void k_score256(const float* __restrict__ enc, const _Float16* __restrict__ W16,
                           const float* __restrict__ db, const float* __restrict__ wv,
                           float* __restrict__ e_part) {
    __shared__ alignas(16) char As0[32768];
    __shared__ alignas(16) char As1[32768];
    __shared__ alignas(16) char Bs0[32768];
    __shared__ alignas(16) char Bs1[32768];

    int fid = blockIdx.x;
    int g = fid >> 4, r = fid & 15;
    int at2 = r >> 3;
    int mt2 = g * 8 + (r & 7);
    if (mt2 >= MT2) return;

    const int tid  = threadIdx.x;
    const int lane = tid & 63;
    const int w    = tid >> 6;       // wave 0..7
    const int wm   = w >> 2;         // wave M-half (0..1): rows wm*128..+128
    const int wn   = w & 3;          // wave N-quarter (0..3): cols wn*64..+64
    const int m0   = mt2 * 256;
    const int a0   = at2 * 256;

    const char* wb = (const char*)W16 + (size_t)(at2 * 2 * KT) * TILE_BYTES;

    const int lr    = lane & 15;
    const int lk2   = (lane >> 4) * 16;
    const int wmoff = wm * 16384;
    const int wnoff = (wn >> 1) * 16384;
    const int wnrow = (wn & 1) * 64;
    const int o     = tid * 16;               // B staging byte offset (linear)

    // A staging geometry: row = tid>>1 (0..255), col-half = (tid&1)*32 floats of 64.
    const int arow  = tid >> 1;
    const float* abase = enc + (size_t)(m0 + arow) * ED + (tid & 1) * 32;
    char* const awbase = ((arow >> 7) ? (char*)0 : (char*)0);  // (computed per-buffer below)
    const int arr   = arow & 127;
    const int astrip = (arow >> 7) * 16384;
    const int acb   = (tid & 1) * 64;          // byte col base within 128B row

    f32x4 acc[8][4];
#pragma unroll
    for (int rb = 0; rb < 8; ++rb)
#pragma unroll
        for (int cb = 0; cb < 4; ++cb) acc[rb][cb] = (f32x4){0.f, 0.f, 0.f, 0.f};

    float4 va0, va1, va2, va3, va4, va5, va6, va7;

#define STAGE_A_LOAD(kt)                                        \
    {                                                           \
        const float* ap = abase + (kt) * 64;                    \
        va0 = *(const float4*)(ap + 0);                         \
        va1 = *(const float4*)(ap + 4);                         \
        va2 = *(const float4*)(ap + 8);                         \
        va3 = *(const float4*)(ap + 12);                        \
        va4 = *(const float4*)(ap + 16);                        \
        va5 = *(const float4*)(ap + 20);                        \
        va6 = *(const float4*)(ap + 24);                        \
        va7 = *(const float4*)(ap + 28);                        \
    }

#define STAGE_A_WRITE(dst)                                      \
    {                                                           \
        char* ab = (dst) + astrip;                              \
        *(f16x8*)(ab + swz(arr, acb + 0))  = cvt8(va0, va1);    \
        *(f16x8*)(ab + swz(arr, acb + 16)) = cvt8(va2, va3);    \
        *(f16x8*)(ab + swz(arr, acb + 32)) = cvt8(va4, va5);    \
        *(f16x8*)(ab + swz(arr, acb + 48)) = cvt8(va6, va7);    \
    }

#define STAGE_B(kt, dB)                                         \
    {                                                           \
        const char* ws_ = wb + (kt) * TILE_BYTES + o;           \
        GLD16(ws_,                          (dB) + o);          \
        GLD16(ws_ + 8192,                   (dB) + o + 8192);   \
        GLD16(ws_ + KT * TILE_BYTES,        (dB) + o + 16384);  \
        GLD16(ws_ + KT * TILE_BYTES + 8192, (dB) + o + 24576);  \
    }

#define COMPUTE(sA, sB)                                                          \
    {                                                                            \
        _Pragma("unroll")                                                        \
        for (int kb = 0; kb < 2; ++kb) {                                         \
            f16x8 aF[8], bF[4];                                                  \
            _Pragma("unroll")                                                    \
            for (int rb = 0; rb < 8; ++rb)                                       \
                aF[rb] = *(const f16x8*)((sA) + wmoff + swz(rb * 16 + lr, kb * 64 + lk2)); \
            _Pragma("unroll")                                                    \
            for (int cb = 0; cb < 4; ++cb)                                       \
                bF[cb] = *(const f16x8*)((sB) + wnoff + swz(wnrow + cb * 16 + lr, kb * 64 + lk2)); \
            __builtin_amdgcn_s_setprio(1);                                       \
            _Pragma("unroll")                                                    \
            for (int rb = 0; rb < 8; ++rb)                                       \
                _Pragma("unroll")                                                \
                for (int cb = 0; cb < 4; ++cb)                                   \
                    acc[rb][cb] = __builtin_amdgcn_mfma_f32_16x16x32_f16(        \
                        aF[rb], bF[cb], acc[rb][cb], 0, 0, 0);                   \
            __builtin_amdgcn_s_setprio(0);                                       \
        }                                                                        \
    }

#define ITER(kt, Acur, Bcur, Anxt, Bnxt)                        \
    STAGE_A_LOAD(kt + 1);                                       \
    STAGE_B(kt + 1, Bnxt);                                      \
    __builtin_amdgcn_sched_barrier(0);                          \
    COMPUTE(Acur, Bcur);                                        \
    __builtin_amdgcn_sched_barrier(0);                          \
    STAGE_A_WRITE(Anxt);                                        \
    __syncthreads();

    // prologue: tile 0
    STAGE_A_LOAD(0);
    STAGE_B(0, Bs0);
    STAGE_A_WRITE(As0);
    __syncthreads();

    ITER(0, As0, Bs0, As1, Bs1)
    ITER(1, As1, Bs1, As0, Bs0)
    ITER(2, As0, Bs0, As1, Bs1)
    ITER(3, As1, Bs1, As0, Bs0)
    ITER(4, As0, Bs0, As1, Bs1)
    ITER(5, As1, Bs1, As0, Bs0)
    ITER(6, As0, Bs0, As1, Bs1)
    COMPUTE(As1, Bs1);
    __syncthreads();
#undef ITER
#undef COMPUTE
#undef STAGE_B
#undef STAGE_A_WRITE
#undef STAGE_A_LOAD

    // epilogue: rs = sum over 64 cols of w_v*tanh(acc+db); shfl-reduce 16 lanes;
    // cross-wave (4 N-quarters) reduce via e_red overlaid on As0 (idle now).
    float* e_red = (float*)As0;   // [4][256]
    const int lg = lane >> 4;
    float wvv[4];
#pragma unroll
    for (int cb = 0; cb < 4; ++cb) wvv[cb] = wv[a0 + wn * 64 + cb * 16 + lr];

#pragma unroll
    for (int rb = 0; rb < 8; ++rb) {
#pragma unroll
        for (int i = 0; i < 4; ++i) {
            int row_local = wm * 128 + rb * 16 + lg * 4 + i;  // C/D: row=(lane>>4)*4+reg
            int m = m0 + row_local;
            int n = m / TI;
            const float* dbp = db + (size_t)n * AD + a0 + wn * 64;
            float rs = 0.f;
#pragma unroll
            for (int cb = 0; cb < 4; ++cb) {
                float s = acc[rb][cb][i] + dbp[cb * 16 + lr];  // col = lane&15
                rs += fast_tanh(s) * wvv[cb];
            }
            rs += __shfl_xor(rs, 1);
            rs += __shfl_xor(rs, 2);
            rs += __shfl_xor(rs, 4);
            rs += __shfl_xor(rs, 8);
            if (lr == 0) e_red[wn * 256 + row_local] = rs;
        }
    }
    __syncthreads();
    if (tid < 256)
        e_part[(size_t)at2 * M_TOT + m0 + tid] =
            e_red[tid] + e_red[256 + tid] + e_red[512 + tid] + e_red[768 + tid];
}

// ---------------- standalone decdb (fallback path only) ----------------
__global__ void k_decdb(const float* __restrict__ dec_prev,
                        const float* __restrict__ W_dec,
                        const float* __restrict__ b_enc,
                        float* __restrict__ db) {
    int n = blockIdx.x;
    __shared__ float xd[ED];
    for (int k = threadIdx.x; k < ED; k += 256) xd[k] = dec_prev[n * ED + k];
    __syncthreads();
    for (int a = threadIdx.x; a < AD; a += 256) {
        const float* wr = W_dec + (size_t)a * ED;
        float s = 0.f;
#pragma unroll 8
        for (int k = 0; k < ED; k += 4) {
            float4 w = *(const float4*)(wr + k);
            s += xd[k] * w.x + xd[k + 1] * w.y + xd[k + 2] * w.z + xd[k + 3] * w.w;
        }
        db[n * AD + a] = s + b_enc[a];
    }
}

// ---------------- fallback fp32 GEMM (convert-in-kernel) if ws too small ----------------
__launch_bounds__(256, 2)
__global__ void k_score_fb(const float* __restrict__ X, const float* __restrict__ W,
                           const float* __restrict__ db, const float* __restrict__ wv,
                           float* __restrict__ e_part) {
    __shared__ alignas(16) _Float16 Xs[128][72];
    __shared__ alignas(16) _Float16 Ws[128][72];
    __shared__ float e_red[2][128];

    const int tid = threadIdx.x, lane = tid & 63, wid = tid >> 6;
    const int wr = wid >> 1, wc = wid & 1;
    const int m0 = blockIdx.x * 128, a0 = blockIdx.y * 128;

    f32x4 acc[4][4];
#pragma unroll
    for (int rb = 0; rb < 4; ++rb)
#pragma unroll
        for (int cb = 0; cb < 4; ++cb) acc[rb][cb] = (f32x4){0.f, 0.f, 0.f, 0.f};

    const int lr = lane & 15;
    const int lk = (lane >> 4) << 3;

    for (int kt = 0; kt < ED; kt += 64) {
#pragma unroll
        for (int i = 0; i < 4; ++i) {
            int idx = tid + i * 256, r = idx >> 3, c = (idx & 7) << 3;
            const float* gx = X + (size_t)(m0 + r) * ED + kt + c;
            float4 x0 = *(const float4*)gx, x1 = *(const float4*)(gx + 4);
            *(f16x8*)&Xs[r][c] = cvt8(x0, x1);
            const float* gw = W + (size_t)(a0 + r) * ED + kt + c;
            float4 w0 = *(const float4*)gw, w1 = *(const float4*)(gw + 4);
            *(f16x8*)&Ws[r][c] = cvt8(w0, w1);
        }
        __syncthreads();
#pragma unroll
        for (int kb = 0; kb < 64; kb += 32) {
            f16x8 aF[4], bF[4];
#pragma unroll
            for (int rb = 0; rb < 4; ++rb) aF[rb] = *(const f16x8*)&Xs[wr * 64 + rb * 16 + lr][kb + lk];
#pragma unroll
            for (int cb = 0; cb < 4; ++cb) bF[cb] = *(const f16x8*)&Ws[wc * 64 + cb * 16 + lr][kb + lk];
#pragma unroll
            for (int rb = 0; rb < 4; ++rb)
#pragma unroll
                for (int cb = 0; cb < 4; ++cb)
                    acc[rb][cb] = __builtin_amdgcn_mfma_f32_16x16x32_f16(aF[rb], bF[cb], acc[rb][cb], 0, 0, 0);
        }
        __syncthreads();
    }

    const int lg = lane >> 4;
    float wvv[4];
#pragma unroll
    for (int cb = 0; cb < 4; ++cb) wvv[cb] = wv[a0 + wc * 64 + cb * 16 + lr];
#pragma unroll
    for (int rb = 0; rb < 4; ++rb) {
#pragma unroll
        for (int i = 0; i < 4; ++i) {
            int row_local = wr * 64 + rb * 16 + lg * 4 + i;
            int m = m0 + row_local;
            int n = m / TI;
            const float* dbp = db + (size_t)n * AD + a0 + wc * 64;
            float rs = 0.f;
#pragma unroll
            for (int cb = 0; cb < 4; ++cb) {
                float s = acc[rb][cb][i] + dbp[cb * 16 + lr];
                rs += fast_tanh(s) * wvv[cb];
            }
            rs += __shfl_xor(rs, 1);
            rs += __shfl_xor(rs, 2);
            rs += __shfl_xor(rs, 4);
            rs += __shfl_xor(rs, 8);
            if (lr == 0) e_red[wc][row_local] = rs;
        }
    }
    __syncthreads();
    if (tid < 128)
        e_part[(size_t)blockIdx.y * M_TOT + m0 + tid] = e_red[0][tid] + e_red[1][tid];
}

// ---------------- Kernel 3: masked softmax over t, per n ----------------
__global__ void k_softmax(const float* __restrict__ e_part,
                          const int* __restrict__ enc_len,
                          float* __restrict__ ali, int nparts) {
    int n = blockIdx.x;
    int len = enc_len[n];
    __shared__ float se[TI];
    __shared__ float redm[4];
    __shared__ float reds[4];
    int tid = threadIdx.x;
    int lane = tid & 63, wid = tid >> 6;

    for (int t = tid; t < TI; t += 256) {
        float s = 0.f;
        for (int p = 0; p < nparts; ++p) s += e_part[(size_t)p * M_TOT + n * TI + t];
        se[t] = s;
    }
    __syncthreads();

    float mx = -1e30f;
    for (int t = tid; t < len; t += 256) mx = fmaxf(mx, se[t]);
#pragma unroll
    for (int o = 32; o >= 1; o >>= 1) mx = fmaxf(mx, __shfl_xor(mx, o));
    if (lane == 0) redm[wid] = mx;
    __syncthreads();
    mx = fmaxf(fmaxf(redm[0], redm[1]), fmaxf(redm[2], redm[3]));

    float sm = 0.f;
    for (int t = tid; t < len; t += 256) {
        float ex = __expf(se[t] - mx);
        se[t] = ex;
        sm += ex;
    }
#pragma unroll
    for (int o = 32; o >= 1; o >>= 1) sm += __shfl_xor(sm, o);
    if (lane == 0) reds[wid] = sm;
    __syncthreads();
    float inv = 1.f / (reds[0] + reds[1] + reds[2] + reds[3]);

    for (int t = tid; t < TI; t += 256)
        ali[n * TI + t] = (t < len) ? se[t] * inv : 0.f;
}

// ---------------- Kernel 4: ctx partials over t-chunks (fp32 enc) ----------------
__global__ void k_ctxpart(const float* __restrict__ enc,
                          const float* __restrict__ ali,
                          float* __restrict__ cpart) {
    int s = blockIdx.x;   // 0..NSPLIT-1
    int n = blockIdx.y;   // 0..31
    int d0 = threadIdx.x * 2;
    const float* base = enc + ((size_t)n * TI + s * TCHUNK) * ED + d0;
    const float* ap = ali + n * TI + s * TCHUNK;
    float ax = 0.f, ay = 0.f;
#pragma unroll 5
    for (int t = 0; t < TCHUNK; ++t) {
        float a = ap[t];
        float2 v = *(const float2*)(base + (size_t)t * ED);
        ax = fmaf(a, v.x, ax);
        ay = fmaf(a, v.y, ay);
    }
    float2 r; r.x = ax; r.y = ay;
    *(float2*)&cpart[((size_t)(n * NSPLIT + s)) * ED + d0] = r;
}

// ---------------- Kernel 5: reduce ctx partials ----------------
__global__ void k_ctxred(const float* __restrict__ cpart, float* __restrict__ ctx) {
    int n = blockIdx.x;
    for (int d = threadIdx.x; d < ED; d += 256) {
        float sum = 0.f;
#pragma unroll
        for (int s = 0; s < NSPLIT; ++s) sum += cpart[((size_t)(n * NSPLIT + s)) * ED + d];
        ctx[(size_t)n * ED + d] = sum;
    }
}

extern "C" void kernel_launch(void* const* d_in, const int* in_sizes, int n_in,
                              void* d_out, int out_size, void* d_ws, size_t ws_size,
                              hipStream_t stream) {
    const float* enc_pad  = (const float*)d_in[0];
    const int*   enc_len  = (const int*)d_in[1];
    const float* dec_prev = (const float*)d_in[2];
    // d_in[3] = ali_prev (unused by reference)
    const float* W_enc    = (const float*)d_in[4];
    const float* b_enc    = (const float*)d_in[5];
    const float* W_dec    = (const float*)d_in[6];
    const float* w_v      = (const float*)d_in[7];

    float* out = (float*)d_out;
    float* ali = out;              // 64000 floats
    float* ctx = out + M_TOT;      // 16384 floats

    float* ws     = (float*)d_ws;
    float* db     = ws;                          // 32*512            = 16384
    float* e_part = ws + NB * AD;                // 4*64000 (<=4 parts)
    float* cpart  = e_part + 4 * M_TOT;          // 32*40*512         = 655360
    size_t fp_floats = (size_t)NB * AD + 4 * M_TOT + (size_t)NB * NSPLIT * ED;  // 927744
    _Float16* W16 = (_Float16*)((char*)d_ws + fp_floats * 4);
    size_t need = fp_floats * 4 + (size_t)32 * TILE_BYTES;   // ~4.2 MB
    bool big = ws_size >= need;

    if (big) {
        hipLaunchKernelGGL(k_wconvert, dim3(160), dim3(256), 0, stream,
                           W_enc, W16, dec_prev, W_dec, b_enc, db);
        hipLaunchKernelGGL(k_score256, dim3(512), dim3(512), 0, stream,
                           enc_pad, W16, db, w_v, e_part);
        hipLaunchKernelGGL(k_softmax, dim3(NB), dim3(256), 0, stream, e_part, enc_len, ali, 2);
    } else {
        hipLaunchKernelGGL(k_decdb, dim3(NB), dim3(256), 0, stream, dec_prev, W_dec, b_enc, db);
        hipLaunchKernelGGL(k_score_fb, dim3(M_TOT / 128, 4), dim3(256), 0, stream,
                           enc_pad, W_enc, db, w_v, e_part);
        hipLaunchKernelGGL(k_softmax, dim3(NB), dim3(256), 0, stream, e_part, enc_len, ali, 4);
    }
    hipLaunchKernelGGL(k_ctxpart, dim3(NSPLIT, NB), dim3(256), 0, stream, enc_pad, ali, cpart);
    hipLaunchKernelGGL(k_ctxred, dim3(NB), dim3(256), 0, stream, cpart, ctx);
}

// Round 6
// 138.984 us; speedup vs baseline: 1.1975x; 1.1975x over previous
//
#include <hip/hip_runtime.h>
#include <stdint.h>

// CtxAttention: additive attention (Bahdanau).
//   e[n,t]  = sum_a w_v[a] * tanh( enc_pad[n,t,:]·W_enc[a,:] + b_enc[a] + dec_prev[n,:]·W_dec[a,:] )
//   ali     = softmax_t(mask(e));  ctx[n,:] = sum_t ali[n,t] * enc_pad[n,t,:]
// Round-6: k_score256 REVERTED to round-3/4 GLD16 version (round-5 reg-staging spilled:
// launch_bounds cap 128 VGPR vs ~200 live -> 51 MB scratch writes, 133 us).
// k_convert fixed: 8 named float4 loads + sched_barrier(0) hard fence, single-shot per
// thread (no loop-carried store-WAR) -> expect HBM-bound ~33 us instead of 88.

#define NB  32
#define TI  2000
#define ED  512
#define AD  512
#define M_TOT (NB * TI)          // 64000
#define NSPLIT 20
#define TCHUNK (TI / NSPLIT)     // 100
#define MT  500                  // 128-row m-tiles (convert granularity)
#define MT2 250                  // 256-row m-tiles (score granularity)
#define KT  8                    // k-tiles of 64
#define TILE_BYTES  16384        // 128 rows x 64 halves x 2B
#define TILE_HALVES 8192

using f16x8 = __attribute__((ext_vector_type(8))) _Float16;
using f32x4 = __attribute__((ext_vector_type(4))) float;

// swizzle within a 128x64-half tile; row r (0..127), byte-col c (16B aligned, 0..127)
__device__ __forceinline__ int swz(int r, int c) { return (r * 128 + c) ^ ((r & 7) << 4); }

#define GLD16(g, l)                                                     \
    __builtin_amdgcn_global_load_lds(                                   \
        (const __attribute__((address_space(1))) void*)(g),             \
        (__attribute__((address_space(3))) void*)(l), 16, 0, 0)

__device__ __forceinline__ float fast_tanh(float s) {
    s = fminf(fmaxf(s, -15.f), 15.f);
    float t = __expf(2.f * s);
    return __fdividef(t - 1.f, t + 1.f);
}

__device__ __forceinline__ f16x8 cvt8(float4 a, float4 b) {
    f16x8 h;
    h[0] = (_Float16)a.x; h[1] = (_Float16)a.y; h[2] = (_Float16)a.z; h[3] = (_Float16)a.w;
    h[4] = (_Float16)b.x; h[5] = (_Float16)b.y; h[6] = (_Float16)b.z; h[7] = (_Float16)b.w;
    return h;
}

// ---------------- Kernel 0: convert enc_pad / W_enc -> tiled swizzled fp16; + fused decdb ----
// bx in [0,4000): X tile (mt = bx>>3, kt = bx&7); [4000,4032): W tile; [4032,4064): decdb.
__launch_bounds__(256)
__global__ void k_convert(const float* __restrict__ enc, const float* __restrict__ Wenc,
                          _Float16* __restrict__ X16, _Float16* __restrict__ W16,
                          const float* __restrict__ dec_prev, const float* __restrict__ W_dec,
                          const float* __restrict__ b_enc, float* __restrict__ db) {
    __shared__ float xd[ED];
    int bx = blockIdx.x;
    int tid = threadIdx.x;
    if (bx >= MT * KT + 32) {
        // ---- decdb: db[n][a] = dec_prev[n,:]·W_dec[a,:] + b_enc[a] ----
        int n = bx - (MT * KT + 32);
        for (int k = tid; k < ED; k += 256) xd[k] = dec_prev[n * ED + k];
        __syncthreads();
        for (int a = tid; a < AD; a += 256) {
            const float* wr = W_dec + (size_t)a * ED;
            float s = 0.f;
#pragma unroll 8
            for (int k = 0; k < ED; k += 4) {
                float4 w = *(const float4*)(wr + k);
                s += xd[k] * w.x + xd[k + 1] * w.y + xd[k + 2] * w.z + xd[k + 3] * w.w;
            }
            db[n * AD + a] = s + b_enc[a];
        }
        return;
    }
    const float* src;
    char* dstb;
    if (bx < MT * KT) {
        int mt = bx >> 3, kt = bx & 7;
        src  = enc + (size_t)mt * 128 * ED + kt * 64;
        dstb = (char*)(X16 + (size_t)bx * TILE_HALVES);
    } else {
        int wt = bx - MT * KT;
        int at = wt >> 3, kt = wt & 7;
        src  = Wenc + (size_t)at * 128 * ED + kt * 64;
        dstb = (char*)(W16 + (size_t)wt * TILE_HALVES);
    }
    // Thread t covers rows {r, r+32, r+64, r+96} (r = tid>>3), float cols (tid&7)*8..+8.
    // Phase 1: issue ALL 8 independent 16B loads into NAMED registers.
    const int r  = tid >> 3;           // 0..31
    const int c2 = (tid & 7) * 16;     // byte col in f16 tile
    const float* sA = src + (size_t)r * ED + (tid & 7) * 8;
    float4 v0 = *(const float4*)(sA);
    float4 v1 = *(const float4*)(sA + 4);
    float4 v2 = *(const float4*)(sA + 32 * ED);
    float4 v3 = *(const float4*)(sA + 32 * ED + 4);
    float4 v4 = *(const float4*)(sA + 64 * ED);
    float4 v5 = *(const float4*)(sA + 64 * ED + 4);
    float4 v6 = *(const float4*)(sA + 96 * ED);
    float4 v7 = *(const float4*)(sA + 96 * ED + 4);
    // Hard scheduling fence: nothing below may be hoisted above, nothing above sunk below.
    __builtin_amdgcn_sched_barrier(0);
    // Phase 2: convert + swizzled store (swz(r+i*32, c2) == swz(r, c2) + i*4096).
    const int so = swz(r, c2);
    *(f16x8*)(dstb + so)          = cvt8(v0, v1);
    *(f16x8*)(dstb + so + 4096)   = cvt8(v2, v3);
    *(f16x8*)(dstb + so + 8192)   = cvt8(v4, v5);
    *(f16x8*)(dstb + so + 12288)  = cvt8(v6, v7);
}

// ---------------- standalone decdb (fallback path only) ----------------
__global__ void k_decdb(const float* __restrict__ dec_prev,
                        const float* __restrict__ W_dec,
                        const float* __restrict__ b_enc,
                        float* __restrict__ db) {
    int n = blockIdx.x;
    __shared__ float xd[ED];
    for (int k = threadIdx.x; k < ED; k += 256) xd[k] = dec_prev[n * ED + k];
    __syncthreads();
    for (int a = threadIdx.x; a < AD; a += 256) {
        const float* wr = W_dec + (size_t)a * ED;
        float s = 0.f;
#pragma unroll 8
        for (int k = 0; k < ED; k += 4) {
            float4 w = *(const float4*)(wr + k);
            s += xd[k] * w.x + xd[k + 1] * w.y + xd[k + 2] * w.z + xd[k + 3] * w.w;
        }
        db[n * AD + a] = s + b_enc[a];
    }
}

// ---------------- Kernel 2: fused score GEMM, 256x256 tile, 8 waves, dbuf (round-3/4) -------
// grid 512: fid -> g=fid>>4, r=fid&15, at2=r>>3, mt2=g*8+(r&7) (XCD-grouped for X16 L2 reuse).
__device__ __forceinline__ void stage_tiles(const char* xb, const char* wb,
                                            char* dA, char* dB, int kt, int o) {
    const char* xs = xb + kt * TILE_BYTES + o;
    const char* ws = wb + kt * TILE_BYTES + o;
    GLD16(xs,                           dA + o);
    GLD16(xs + 8192,                    dA + o + 8192);
    GLD16(xs + KT * TILE_BYTES,         dA + o + 16384);
    GLD16(xs + KT * TILE_BYTES + 8192,  dA + o + 24576);
    GLD16(ws,                           dB + o);
    GLD16(ws + 8192,                    dB + o + 8192);
    GLD16(ws + KT * TILE_BYTES,         dB + o + 16384);
    GLD16(ws + KT * TILE_BYTES + 8192,  dB + o + 24576);
}

__launch_bounds__(512, 2)
__global__ void k_score256(const _Float16* __restrict__ X16, const _Float16* __restrict__ W16,
                           const float* __restrict__ db, const float* __restrict__ wv,
                           float* __restrict__ e_part) {
    __shared__ alignas(16) char As0[32768];
    __shared__ alignas(16) char As1[32768];
    __shared__ alignas(16) char Bs0[32768];
    __shared__ alignas(16) char Bs1[32768];

    int fid = blockIdx.x;
    int g = fid >> 4, r = fid & 15;
    int at2 = r >> 3;
    int mt2 = g * 8 + (r & 7);
    if (mt2 >= MT2) return;

    const int tid  = threadIdx.x;
    const int lane = tid & 63;
    const int w    = tid >> 6;       // wave 0..7
    const int wm   = w >> 2;         // wave M-half (0..1): rows wm*128..+128
    const int wn   = w & 3;          // wave N-quarter (0..3): cols wn*64..+64
    const int m0   = mt2 * 256;
    const int a0   = at2 * 256;

    const char* xb = (const char*)X16 + (size_t)(mt2 * 2 * KT) * TILE_BYTES;
    const char* wb = (const char*)W16 + (size_t)(at2 * 2 * KT) * TILE_BYTES;

    const int lr    = lane & 15;
    const int lk2   = (lane >> 4) * 16;
    const int wmoff = wm * 16384;
    const int wnoff = (wn >> 1) * 16384;
    const int wnrow = (wn & 1) * 64;
    const int o     = tid * 16;               // staging byte offset (linear)

    f32x4 acc[8][4];
#pragma unroll
    for (int rb = 0; rb < 8; ++rb)
#pragma unroll
        for (int cb = 0; cb < 4; ++cb) acc[rb][cb] = (f32x4){0.f, 0.f, 0.f, 0.f};

#define COMPUTE(sA, sB)                                                          \
    {                                                                            \
        _Pragma("unroll")                                                        \
        for (int kb = 0; kb < 2; ++kb) {                                         \
            f16x8 aF[8], bF[4];                                                  \
            _Pragma("unroll")                                                    \
            for (int rb = 0; rb < 8; ++rb)                                       \
                aF[rb] = *(const f16x8*)((sA) + wmoff + swz(rb * 16 + lr, kb * 64 + lk2)); \
            _Pragma("unroll")                                                    \
            for (int cb = 0; cb < 4; ++cb)                                       \
                bF[cb] = *(const f16x8*)((sB) + wnoff + swz(wnrow + cb * 16 + lr, kb * 64 + lk2)); \
            __builtin_amdgcn_s_setprio(1);                                       \
            _Pragma("unroll")                                                    \
            for (int rb = 0; rb < 8; ++rb)                                       \
                _Pragma("unroll")                                                \
                for (int cb = 0; cb < 4; ++cb)                                   \
                    acc[rb][cb] = __builtin_amdgcn_mfma_f32_16x16x32_f16(        \
                        aF[rb], bF[cb], acc[rb][cb], 0, 0, 0);                   \
            __builtin_amdgcn_s_setprio(0);                                       \
        }                                                                        \
    }

    // prologue + fully unrolled 8-tile double-buffered pipeline
    stage_tiles(xb, wb, As0, Bs0, 0, o); __syncthreads();
    stage_tiles(xb, wb, As1, Bs1, 1, o); COMPUTE(As0, Bs0); __syncthreads();
    stage_tiles(xb, wb, As0, Bs0, 2, o); COMPUTE(As1, Bs1); __syncthreads();
    stage_tiles(xb, wb, As1, Bs1, 3, o); COMPUTE(As0, Bs0); __syncthreads();
    stage_tiles(xb, wb, As0, Bs0, 4, o); COMPUTE(As1, Bs1); __syncthreads();
    stage_tiles(xb, wb, As1, Bs1, 5, o); COMPUTE(As0, Bs0); __syncthreads();
    stage_tiles(xb, wb, As0, Bs0, 6, o); COMPUTE(As1, Bs1); __syncthreads();
    stage_tiles(xb, wb, As1, Bs1, 7, o); COMPUTE(As0, Bs0); __syncthreads();
    COMPUTE(As1, Bs1); __syncthreads();
#undef COMPUTE

    // epilogue: rs = sum over 64 cols of w_v*tanh(acc+db); shfl-reduce 16 lanes;
    // cross-wave (4 N-quarters) reduce via e_red overlaid on As0 (idle now).
    float* e_red = (float*)As0;   // [4][256]
    const int lg = lane >> 4;
    float wvv[4];
#pragma unroll
    for (int cb = 0; cb < 4; ++cb) wvv[cb] = wv[a0 + wn * 64 + cb * 16 + lr];

#pragma unroll
    for (int rb = 0; rb < 8; ++rb) {
#pragma unroll
        for (int i = 0; i < 4; ++i) {
            int row_local = wm * 128 + rb * 16 + lg * 4 + i;  // C/D: row=(lane>>4)*4+reg
            int m = m0 + row_local;
            int n = m / TI;
            const float* dbp = db + (size_t)n * AD + a0 + wn * 64;
            float rs = 0.f;
#pragma unroll
            for (int cb = 0; cb < 4; ++cb) {
                float s = acc[rb][cb][i] + dbp[cb * 16 + lr];  // col = lane&15
                rs += fast_tanh(s) * wvv[cb];
            }
            rs += __shfl_xor(rs, 1);
            rs += __shfl_xor(rs, 2);
            rs += __shfl_xor(rs, 4);
            rs += __shfl_xor(rs, 8);
            if (lr == 0) e_red[wn * 256 + row_local] = rs;
        }
    }
    __syncthreads();
    if (tid < 256)
        e_part[(size_t)at2 * M_TOT + m0 + tid] =
            e_red[tid] + e_red[256 + tid] + e_red[512 + tid] + e_red[768 + tid];
}

// ---------------- fallback fp32 GEMM (convert-in-kernel) if ws too small ----------------
__launch_bounds__(256, 2)
__global__ void k_score_fb(const float* __restrict__ X, const float* __restrict__ W,
                           const float* __restrict__ db, const float* __restrict__ wv,
                           float* __restrict__ e_part) {
    __shared__ alignas(16) _Float16 Xs[128][72];
    __shared__ alignas(16) _Float16 Ws[128][72];
    __shared__ float e_red[2][128];

    const int tid = threadIdx.x, lane = tid & 63, wid = tid >> 6;
    const int wr = wid >> 1, wc = wid & 1;
    const int m0 = blockIdx.x * 128, a0 = blockIdx.y * 128;

    f32x4 acc[4][4];
#pragma unroll
    for (int rb = 0; rb < 4; ++rb)
#pragma unroll
        for (int cb = 0; cb < 4; ++cb) acc[rb][cb] = (f32x4){0.f, 0.f, 0.f, 0.f};

    const int lr = lane & 15;
    const int lk = (lane >> 4) << 3;

    for (int kt = 0; kt < ED; kt += 64) {
#pragma unroll
        for (int i = 0; i < 4; ++i) {
            int idx = tid + i * 256, r = idx >> 3, c = (idx & 7) << 3;
            const float* gx = X + (size_t)(m0 + r) * ED + kt + c;
            float4 x0 = *(const float4*)gx, x1 = *(const float4*)(gx + 4);
            *(f16x8*)&Xs[r][c] = cvt8(x0, x1);
            const float* gw = W + (size_t)(a0 + r) * ED + kt + c;
            float4 w0 = *(const float4*)gw, w1 = *(const float4*)(gw + 4);
            *(f16x8*)&Ws[r][c] = cvt8(w0, w1);
        }
        __syncthreads();
#pragma unroll
        for (int kb = 0; kb < 64; kb += 32) {
            f16x8 aF[4], bF[4];
#pragma unroll
            for (int rb = 0; rb < 4; ++rb) aF[rb] = *(const f16x8*)&Xs[wr * 64 + rb * 16 + lr][kb + lk];
#pragma unroll
            for (int cb = 0; cb < 4; ++cb) bF[cb] = *(const f16x8*)&Ws[wc * 64 + cb * 16 + lr][kb + lk];
#pragma unroll
            for (int rb = 0; rb < 4; ++rb)
#pragma unroll
                for (int cb = 0; cb < 4; ++cb)
                    acc[rb][cb] = __builtin_amdgcn_mfma_f32_16x16x32_f16(aF[rb], bF[cb], acc[rb][cb], 0, 0, 0);
        }
        __syncthreads();
    }

    const int lg = lane >> 4;
    float wvv[4];
#pragma unroll
    for (int cb = 0; cb < 4; ++cb) wvv[cb] = wv[a0 + wc * 64 + cb * 16 + lr];
#pragma unroll
    for (int rb = 0; rb < 4; ++rb) {
#pragma unroll
        for (int i = 0; i < 4; ++i) {
            int row_local = wr * 64 + rb * 16 + lg * 4 + i;
            int m = m0 + row_local;
            int n = m / TI;
            const float* dbp = db + (size_t)n * AD + a0 + wc * 64;
            float rs = 0.f;
#pragma unroll
            for (int cb = 0; cb < 4; ++cb) {
                float s = acc[rb][cb][i] + dbp[cb * 16 + lr];
                rs += fast_tanh(s) * wvv[cb];
            }
            rs += __shfl_xor(rs, 1);
            rs += __shfl_xor(rs, 2);
            rs += __shfl_xor(rs, 4);
            rs += __shfl_xor(rs, 8);
            if (lr == 0) e_red[wc][row_local] = rs;
        }
    }
    __syncthreads();
    if (tid < 128)
        e_part[(size_t)blockIdx.y * M_TOT + m0 + tid] = e_red[0][tid] + e_red[1][tid];
}

// ---------------- Kernel 3: masked softmax over t, per n ----------------
__global__ void k_softmax(const float* __restrict__ e_part,
                          const int* __restrict__ enc_len,
                          float* __restrict__ ali, int nparts) {
    int n = blockIdx.x;
    int len = enc_len[n];
    __shared__ float se[TI];
    __shared__ float redm[4];
    __shared__ float reds[4];
    int tid = threadIdx.x;
    int lane = tid & 63, wid = tid >> 6;

    for (int t = tid; t < TI; t += 256) {
        float s = 0.f;
        for (int p = 0; p < nparts; ++p) s += e_part[(size_t)p * M_TOT + n * TI + t];
        se[t] = s;
    }
    __syncthreads();

    float mx = -1e30f;
    for (int t = tid; t < len; t += 256) mx = fmaxf(mx, se[t]);
#pragma unroll
    for (int o = 32; o >= 1; o >>= 1) mx = fmaxf(mx, __shfl_xor(mx, o));
    if (lane == 0) redm[wid] = mx;
    __syncthreads();
    mx = fmaxf(fmaxf(redm[0], redm[1]), fmaxf(redm[2], redm[3]));

    float sm = 0.f;
    for (int t = tid; t < len; t += 256) {
        float ex = __expf(se[t] - mx);
        se[t] = ex;
        sm += ex;
    }
#pragma unroll
    for (int o = 32; o >= 1; o >>= 1) sm += __shfl_xor(sm, o);
    if (lane == 0) reds[wid] = sm;
    __syncthreads();
    float inv = 1.f / (reds[0] + reds[1] + reds[2] + reds[3]);

    for (int t = tid; t < TI; t += 256)
        ali[n * TI + t] = (t < len) ? se[t] * inv : 0.f;
}

// ---------------- Kernel 4a: ctx partials from fp16 tiled X16 ----------------
__global__ void k_ctxpart16(const _Float16* __restrict__ X16, const float* __restrict__ ali,
                            float* __restrict__ cpart) {
    int s = blockIdx.x, n = blockIdx.y;
    int tid = threadIdx.x;
    int sub = tid >> 6;            // t-phase 0..3
    int dc  = (tid & 63) * 8;      // 8 d-cols per thread
    int ktile = dc >> 6;
    int c2 = (dc & 63) * 2;
    float acc[8] = {0.f, 0.f, 0.f, 0.f, 0.f, 0.f, 0.f, 0.f};
    for (int t = s * TCHUNK + sub; t < (s + 1) * TCHUNK; t += 4) {
        int m = n * TI + t;
        int mt2 = m >> 7, r = m & 127;
        const char* p = (const char*)(X16 + (size_t)(mt2 * KT + ktile) * TILE_HALVES);
        f16x8 v = *(const f16x8*)(p + swz(r, c2));
        float a = ali[m];
#pragma unroll
        for (int j = 0; j < 8; ++j) acc[j] = fmaf(a, (float)v[j], acc[j]);
    }
    __shared__ float red[4][ED];
#pragma unroll
    for (int j = 0; j < 8; ++j) red[sub][dc + j] = acc[j];
    __syncthreads();
    if (sub == 0) {
#pragma unroll
        for (int j = 0; j < 8; ++j) {
            float sm = red[0][dc + j] + red[1][dc + j] + red[2][dc + j] + red[3][dc + j];
            cpart[((size_t)(n * NSPLIT + s)) * ED + dc + j] = sm;
        }
    }
}

// ---------------- Kernel 4b: fp32 ctx partials (fallback) ----------------
__global__ void k_ctxpart(const float* __restrict__ enc,
                          const float* __restrict__ ali,
                          float* __restrict__ cpart) {
    int s = blockIdx.x;
    int n = blockIdx.y;
    int d0 = threadIdx.x * 2;
    const float* base = enc + ((size_t)n * TI + s * TCHUNK) * ED + d0;
    const float* ap = ali + n * TI + s * TCHUNK;
    float ax = 0.f, ay = 0.f;
#pragma unroll 4
    for (int t = 0; t < TCHUNK; ++t) {
        float a = ap[t];
        float2 v = *(const float2*)(base + (size_t)t * ED);
        ax = fmaf(a, v.x, ax);
        ay = fmaf(a, v.y, ay);
    }
    float2 r; r.x = ax; r.y = ay;
    *(float2*)&cpart[((size_t)(n * NSPLIT + s)) * ED + d0] = r;
}

// ---------------- Kernel 5: reduce ctx partials ----------------
__global__ void k_ctxred(const float* __restrict__ cpart, float* __restrict__ ctx) {
    int n = blockIdx.x;
    for (int d = threadIdx.x; d < ED; d += 256) {
        float sum = 0.f;
#pragma unroll
        for (int s = 0; s < NSPLIT; ++s) sum += cpart[((size_t)(n * NSPLIT + s)) * ED + d];
        ctx[(size_t)n * ED + d] = sum;
    }
}

extern "C" void kernel_launch(void* const* d_in, const int* in_sizes, int n_in,
                              void* d_out, int out_size, void* d_ws, size_t ws_size,
                              hipStream_t stream) {
    const float* enc_pad  = (const float*)d_in[0];
    const int*   enc_len  = (const int*)d_in[1];
    const float* dec_prev = (const float*)d_in[2];
    // d_in[3] = ali_prev (unused by reference)
    const float* W_enc    = (const float*)d_in[4];
    const float* b_enc    = (const float*)d_in[5];
    const float* W_dec    = (const float*)d_in[6];
    const float* w_v      = (const float*)d_in[7];

    float* out = (float*)d_out;
    float* ali = out;              // 64000 floats
    float* ctx = out + M_TOT;      // 16384 floats

    float* ws     = (float*)d_ws;
    float* db     = ws;                          // 32*512
    float* e_part = ws + NB * AD;                // up to 4*64000
    float* cpart  = e_part + 4 * M_TOT;          // 32*20*512
    size_t fp_floats = (size_t)NB * AD + 4 * M_TOT + (size_t)NB * NSPLIT * ED;  // 600064
    _Float16* X16 = (_Float16*)((char*)d_ws + fp_floats * 4);
    _Float16* W16 = X16 + (size_t)MT * KT * TILE_HALVES;
    size_t need = fp_floats * 4 + ((size_t)MT * KT + 32) * TILE_BYTES;
    bool big = ws_size >= need;

    if (big) {
        hipLaunchKernelGGL(k_convert, dim3(MT * KT + 64), dim3(256), 0, stream,
                           enc_pad, W_enc, X16, W16, dec_prev, W_dec, b_enc, db);
        hipLaunchKernelGGL(k_score256, dim3(512), dim3(512), 0, stream,
                           X16, W16, db, w_v, e_part);
        hipLaunchKernelGGL(k_softmax, dim3(NB), dim3(256), 0, stream, e_part, enc_len, ali, 2);
        hipLaunchKernelGGL(k_ctxpart16, dim3(NSPLIT, NB), dim3(256), 0, stream, X16, ali, cpart);
    } else {
        hipLaunchKernelGGL(k_decdb, dim3(NB), dim3(256), 0, stream, dec_prev, W_dec, b_enc, db);
        hipLaunchKernelGGL(k_score_fb, dim3(M_TOT / 128, 4), dim3(256), 0, stream,
                           enc_pad, W_enc, db, w_v, e_part);
        hipLaunchKernelGGL(k_softmax, dim3(NB), dim3(256), 0, stream, e_part, enc_len, ali, 4);
        hipLaunchKernelGGL(k_ctxpart, dim3(NSPLIT, NB), dim3(256), 0, stream, enc_pad, ali, cpart);
    }
    hipLaunchKernelGGL(k_ctxred, dim3(NB), dim3(256), 0, stream, cpart, ctx);
}

// Round 7
// 138.607 us; speedup vs baseline: 1.2007x; 1.0027x over previous
//
#include <hip/hip_runtime.h>
#include <stdint.h>

// CtxAttention: additive attention (Bahdanau).
//   e[n,t]  = sum_a w_v[a] * tanh( enc_pad[n,t,:]·W_enc[a,:] + b_enc[a] + dec_prev[n,:]·W_dec[a,:] )
//   ali     = softmax_t(mask(e));  ctx[n,:] = sum_t ali[n,t] * enc_pad[n,t,:]
// Round-7: k_convert rewritten around global_load_lds (VGPR-staged ILP failed twice:
// rounds 4/6 both pinned at VGPR=32, 2-deep chains, 1.5 TB/s, 88 us). GLD16 gives
// 8 outstanding 1KB loads/wave with zero VGPR pressure -> HBM-bound convert.
// k_score256 / softmax / ctxpart16 / ctxred unchanged (round-3/4 proven).

#define NB  32
#define TI  2000
#define ED  512
#define AD  512
#define M_TOT (NB * TI)          // 64000
#define NSPLIT 20
#define TCHUNK (TI / NSPLIT)     // 100
#define MT  500                  // 128-row m-tiles (convert granularity)
#define MT2 250                  // 256-row m-tiles (score granularity)
#define KT  8                    // k-tiles of 64
#define TILE_BYTES  16384        // 128 rows x 64 halves x 2B
#define TILE_HALVES 8192

using f16x8 = __attribute__((ext_vector_type(8))) _Float16;
using f16x4 = __attribute__((ext_vector_type(4))) _Float16;
using f32x4 = __attribute__((ext_vector_type(4))) float;

// swizzle within a 128x64-half tile; row r (0..127), byte-col c (16B aligned, 0..127)
__device__ __forceinline__ int swz(int r, int c) { return (r * 128 + c) ^ ((r & 7) << 4); }

#define GLD16(g, l)                                                     \
    __builtin_amdgcn_global_load_lds(                                   \
        (const __attribute__((address_space(1))) void*)(g),             \
        (__attribute__((address_space(3))) void*)(l), 16, 0, 0)

__device__ __forceinline__ float fast_tanh(float s) {
    s = fminf(fmaxf(s, -15.f), 15.f);
    float t = __expf(2.f * s);
    return __fdividef(t - 1.f, t + 1.f);
}

__device__ __forceinline__ f16x8 cvt8(float4 a, float4 b) {
    f16x8 h;
    h[0] = (_Float16)a.x; h[1] = (_Float16)a.y; h[2] = (_Float16)a.z; h[3] = (_Float16)a.w;
    h[4] = (_Float16)b.x; h[5] = (_Float16)b.y; h[6] = (_Float16)b.z; h[7] = (_Float16)b.w;
    return h;
}

// ---------------- Kernel 0: convert enc_pad / W_enc -> tiled swizzled fp16; + fused decdb ----
// bx in [0,4000): X tile (mt = bx>>3, kt = bx&7); [4000,4032): W tile; [4032,4064): decdb.
// Phase 1: whole 32 KB fp32 tile -> LDS via 8x GLD16/thread (deep async queue, no VGPRs).
// Phase 2: linear ds_read_b128 (conflict-free), cvt, 8B swizzled global store.
__launch_bounds__(256)
__global__ void k_convert(const float* __restrict__ enc, const float* __restrict__ Wenc,
                          _Float16* __restrict__ X16, _Float16* __restrict__ W16,
                          const float* __restrict__ dec_prev, const float* __restrict__ W_dec,
                          const float* __restrict__ b_enc, float* __restrict__ db) {
    __shared__ alignas(16) float buf[8192];   // 32 KB
    int bx = blockIdx.x;
    int tid = threadIdx.x;
    if (bx >= MT * KT + 32) {
        // ---- decdb: db[n][a] = dec_prev[n,:]·W_dec[a,:] + b_enc[a] ----
        int n = bx - (MT * KT + 32);
        for (int k = tid; k < ED; k += 256) buf[k] = dec_prev[n * ED + k];
        __syncthreads();
        for (int a = tid; a < AD; a += 256) {
            const float* wr = W_dec + (size_t)a * ED;
            float s = 0.f;
#pragma unroll 8
            for (int k = 0; k < ED; k += 4) {
                float4 w = *(const float4*)(wr + k);
                s += buf[k] * w.x + buf[k + 1] * w.y + buf[k + 2] * w.z + buf[k + 3] * w.w;
            }
            db[n * AD + a] = s + b_enc[a];
        }
        return;
    }
    const float* src;
    char* dstb;
    if (bx < MT * KT) {
        int mt = bx >> 3, kt = bx & 7;
        src  = enc + (size_t)mt * 128 * ED + kt * 64;
        dstb = (char*)(X16 + (size_t)bx * TILE_HALVES);
    } else {
        int wt = bx - MT * KT;
        int at = wt >> 3, kt = wt & 7;
        src  = Wenc + (size_t)at * 128 * ED + kt * 64;
        dstb = (char*)(W16 + (size_t)wt * TILE_HALVES);
    }
    // Phase 1: stage tile rows [0,128) x 64 floats into LDS linearly.
    // LDS byte offset o = i*4096 + tid*16  <->  float f = o/4, row = f>>6, col = f&63.
    {
        const float* g = src + (size_t)(tid >> 4) * ED + (tid & 15) * 4;
        char* ldsb = (char*)buf + tid * 16;   // = (buf + wave*1024) + lane*16 : legal GLD16 dest
#pragma unroll
        for (int i = 0; i < 8; ++i)
            GLD16(g + (size_t)i * 16 * ED, ldsb + i * 4096);
    }
    __syncthreads();   // drains vmcnt -> LDS tile complete
    // Phase 2: read back linearly (conflict-free), convert, swizzled 8B stores.
#pragma unroll
    for (int i = 0; i < 8; ++i) {
        float4 v = *(const float4*)((const char*)buf + i * 4096 + tid * 16);
        int r   = i * 16 + (tid >> 4);
        int c16 = ((tid >> 1) & 7) * 16;     // 16B-aligned byte col of this 8B half
        int sub = (tid & 1) * 8;
        f16x4 h;
        h[0] = (_Float16)v.x; h[1] = (_Float16)v.y;
        h[2] = (_Float16)v.z; h[3] = (_Float16)v.w;
        *(f16x4*)(dstb + swz(r, c16) + sub) = h;
    }
}

// ---------------- standalone decdb (fallback path only) ----------------
__global__ void k_decdb(const float* __restrict__ dec_prev,
                        const float* __restrict__ W_dec,
                        const float* __restrict__ b_enc,
                        float* __restrict__ db) {
    int n = blockIdx.x;
    __shared__ float xd[ED];
    for (int k = threadIdx.x; k < ED; k += 256) xd[k] = dec_prev[n * ED + k];
    __syncthreads();
    for (int a = threadIdx.x; a < AD; a += 256) {
        const float* wr = W_dec + (size_t)a * ED;
        float s = 0.f;
#pragma unroll 8
        for (int k = 0; k < ED; k += 4) {
            float4 w = *(const float4*)(wr + k);
            s += xd[k] * w.x + xd[k + 1] * w.y + xd[k + 2] * w.z + xd[k + 3] * w.w;
        }
        db[n * AD + a] = s + b_enc[a];
    }
}

// ---------------- Kernel 2: fused score GEMM, 256x256 tile, 8 waves, dbuf (round-3/4) -------
// grid 512: fid -> g=fid>>4, r=fid&15, at2=r>>3, mt2=g*8+(r&7) (XCD-grouped for X16 L2 reuse).
__device__ __forceinline__ void stage_tiles(const char* xb, const char* wb,
                                            char* dA, char* dB, int kt, int o) {
    const char* xs = xb + kt * TILE_BYTES + o;
    const char* ws = wb + kt * TILE_BYTES + o;
    GLD16(xs,                           dA + o);
    GLD16(xs + 8192,                    dA + o + 8192);
    GLD16(xs + KT * TILE_BYTES,         dA + o + 16384);
    GLD16(xs + KT * TILE_BYTES + 8192,  dA + o + 24576);
    GLD16(ws,                           dB + o);
    GLD16(ws + 8192,                    dB + o + 8192);
    GLD16(ws + KT * TILE_BYTES,         dB + o + 16384);
    GLD16(ws + KT * TILE_BYTES + 8192,  dB + o + 24576);
}

__launch_bounds__(512, 2)
__global__ void k_score256(const _Float16* __restrict__ X16, const _Float16* __restrict__ W16,
                           const float* __restrict__ db, const float* __restrict__ wv,
                           float* __restrict__ e_part) {
    __shared__ alignas(16) char As0[32768];
    __shared__ alignas(16) char As1[32768];
    __shared__ alignas(16) char Bs0[32768];
    __shared__ alignas(16) char Bs1[32768];

    int fid = blockIdx.x;
    int g = fid >> 4, r = fid & 15;
    int at2 = r >> 3;
    int mt2 = g * 8 + (r & 7);
    if (mt2 >= MT2) return;

    const int tid  = threadIdx.x;
    const int lane = tid & 63;
    const int w    = tid >> 6;       // wave 0..7
    const int wm   = w >> 2;         // wave M-half (0..1): rows wm*128..+128
    const int wn   = w & 3;          // wave N-quarter (0..3): cols wn*64..+64
    const int m0   = mt2 * 256;
    const int a0   = at2 * 256;

    const char* xb = (const char*)X16 + (size_t)(mt2 * 2 * KT) * TILE_BYTES;
    const char* wb = (const char*)W16 + (size_t)(at2 * 2 * KT) * TILE_BYTES;

    const int lr    = lane & 15;
    const int lk2   = (lane >> 4) * 16;
    const int wmoff = wm * 16384;
    const int wnoff = (wn >> 1) * 16384;
    const int wnrow = (wn & 1) * 64;
    const int o     = tid * 16;               // staging byte offset (linear)

    f32x4 acc[8][4];
#pragma unroll
    for (int rb = 0; rb < 8; ++rb)
#pragma unroll
        for (int cb = 0; cb < 4; ++cb) acc[rb][cb] = (f32x4){0.f, 0.f, 0.f, 0.f};

#define COMPUTE(sA, sB)                                                          \
    {                                                                            \
        _Pragma("unroll")                                                        \
        for (int kb = 0; kb < 2; ++kb) {                                         \
            f16x8 aF[8], bF[4];                                                  \
            _Pragma("unroll")                                                    \
            for (int rb = 0; rb < 8; ++rb)                                       \
                aF[rb] = *(const f16x8*)((sA) + wmoff + swz(rb * 16 + lr, kb * 64 + lk2)); \
            _Pragma("unroll")                                                    \
            for (int cb = 0; cb < 4; ++cb)                                       \
                bF[cb] = *(const f16x8*)((sB) + wnoff + swz(wnrow + cb * 16 + lr, kb * 64 + lk2)); \
            __builtin_amdgcn_s_setprio(1);                                       \
            _Pragma("unroll")                                                    \
            for (int rb = 0; rb < 8; ++rb)                                       \
                _Pragma("unroll")                                                \
                for (int cb = 0; cb < 4; ++cb)                                   \
                    acc[rb][cb] = __builtin_amdgcn_mfma_f32_16x16x32_f16(        \
                        aF[rb], bF[cb], acc[rb][cb], 0, 0, 0);                   \
            __builtin_amdgcn_s_setprio(0);                                       \
        }                                                                        \
    }

    // prologue + fully unrolled 8-tile double-buffered pipeline
    stage_tiles(xb, wb, As0, Bs0, 0, o); __syncthreads();
    stage_tiles(xb, wb, As1, Bs1, 1, o); COMPUTE(As0, Bs0); __syncthreads();
    stage_tiles(xb, wb, As0, Bs0, 2, o); COMPUTE(As1, Bs1); __syncthreads();
    stage_tiles(xb, wb, As1, Bs1, 3, o); COMPUTE(As0, Bs0); __syncthreads();
    stage_tiles(xb, wb, As0, Bs0, 4, o); COMPUTE(As1, Bs1); __syncthreads();
    stage_tiles(xb, wb, As1, Bs1, 5, o); COMPUTE(As0, Bs0); __syncthreads();
    stage_tiles(xb, wb, As0, Bs0, 6, o); COMPUTE(As1, Bs1); __syncthreads();
    stage_tiles(xb, wb, As1, Bs1, 7, o); COMPUTE(As0, Bs0); __syncthreads();
    COMPUTE(As1, Bs1); __syncthreads();
#undef COMPUTE

    // epilogue: rs = sum over 64 cols of w_v*tanh(acc+db); shfl-reduce 16 lanes;
    // cross-wave (4 N-quarters) reduce via e_red overlaid on As0 (idle now).
    float* e_red = (float*)As0;   // [4][256]
    const int lg = lane >> 4;
    float wvv[4];
#pragma unroll
    for (int cb = 0; cb < 4; ++cb) wvv[cb] = wv[a0 + wn * 64 + cb * 16 + lr];

#pragma unroll
    for (int rb = 0; rb < 8; ++rb) {
#pragma unroll
        for (int i = 0; i < 4; ++i) {
            int row_local = wm * 128 + rb * 16 + lg * 4 + i;  // C/D: row=(lane>>4)*4+reg
            int m = m0 + row_local;
            int n = m / TI;
            const float* dbp = db + (size_t)n * AD + a0 + wn * 64;
            float rs = 0.f;
#pragma unroll
            for (int cb = 0; cb < 4; ++cb) {
                float s = acc[rb][cb][i] + dbp[cb * 16 + lr];  // col = lane&15
                rs += fast_tanh(s) * wvv[cb];
            }
            rs += __shfl_xor(rs, 1);
            rs += __shfl_xor(rs, 2);
            rs += __shfl_xor(rs, 4);
            rs += __shfl_xor(rs, 8);
            if (lr == 0) e_red[wn * 256 + row_local] = rs;
        }
    }
    __syncthreads();
    if (tid < 256)
        e_part[(size_t)at2 * M_TOT + m0 + tid] =
            e_red[tid] + e_red[256 + tid] + e_red[512 + tid] + e_red[768 + tid];
}

// ---------------- fallback fp32 GEMM (convert-in-kernel) if ws too small ----------------
__launch_bounds__(256, 2)
__global__ void k_score_fb(const float* __restrict__ X, const float* __restrict__ W,
                           const float* __restrict__ db, const float* __restrict__ wv,
                           float* __restrict__ e_part) {
    __shared__ alignas(16) _Float16 Xs[128][72];
    __shared__ alignas(16) _Float16 Ws[128][72];
    __shared__ float e_red[2][128];

    const int tid = threadIdx.x, lane = tid & 63, wid = tid >> 6;
    const int wr = wid >> 1, wc = wid & 1;
    const int m0 = blockIdx.x * 128, a0 = blockIdx.y * 128;

    f32x4 acc[4][4];
#pragma unroll
    for (int rb = 0; rb < 4; ++rb)
#pragma unroll
        for (int cb = 0; cb < 4; ++cb) acc[rb][cb] = (f32x4){0.f, 0.f, 0.f, 0.f};

    const int lr = lane & 15;
    const int lk = (lane >> 4) << 3;

    for (int kt = 0; kt < ED; kt += 64) {
#pragma unroll
        for (int i = 0; i < 4; ++i) {
            int idx = tid + i * 256, r = idx >> 3, c = (idx & 7) << 3;
            const float* gx = X + (size_t)(m0 + r) * ED + kt + c;
            float4 x0 = *(const float4*)gx, x1 = *(const float4*)(gx + 4);
            *(f16x8*)&Xs[r][c] = cvt8(x0, x1);
            const float* gw = W + (size_t)(a0 + r) * ED + kt + c;
            float4 w0 = *(const float4*)gw, w1 = *(const float4*)(gw + 4);
            *(f16x8*)&Ws[r][c] = cvt8(w0, w1);
        }
        __syncthreads();
#pragma unroll
        for (int kb = 0; kb < 64; kb += 32) {
            f16x8 aF[4], bF[4];
#pragma unroll
            for (int rb = 0; rb < 4; ++rb) aF[rb] = *(const f16x8*)&Xs[wr * 64 + rb * 16 + lr][kb + lk];
#pragma unroll
            for (int cb = 0; cb < 4; ++cb) bF[cb] = *(const f16x8*)&Ws[wc * 64 + cb * 16 + lr][kb + lk];
#pragma unroll
            for (int rb = 0; rb < 4; ++rb)
#pragma unroll
                for (int cb = 0; cb < 4; ++cb)
                    acc[rb][cb] = __builtin_amdgcn_mfma_f32_16x16x32_f16(aF[rb], bF[cb], acc[rb][cb], 0, 0, 0);
        }
        __syncthreads();
    }

    const int lg = lane >> 4;
    float wvv[4];
#pragma unroll
    for (int cb = 0; cb < 4; ++cb) wvv[cb] = wv[a0 + wc * 64 + cb * 16 + lr];
#pragma unroll
    for (int rb = 0; rb < 4; ++rb) {
#pragma unroll
        for (int i = 0; i < 4; ++i) {
            int row_local = wr * 64 + rb * 16 + lg * 4 + i;
            int m = m0 + row_local;
            int n = m / TI;
            const float* dbp = db + (size_t)n * AD + a0 + wc * 64;
            float rs = 0.f;
#pragma unroll
            for (int cb = 0; cb < 4; ++cb) {
                float s = acc[rb][cb][i] + dbp[cb * 16 + lr];
                rs += fast_tanh(s) * wvv[cb];
            }
            rs += __shfl_xor(rs, 1);
            rs += __shfl_xor(rs, 2);
            rs += __shfl_xor(rs, 4);
            rs += __shfl_xor(rs, 8);
            if (lr == 0) e_red[wc][row_local] = rs;
        }
    }
    __syncthreads();
    if (tid < 128)
        e_part[(size_t)blockIdx.y * M_TOT + m0 + tid] = e_red[0][tid] + e_red[1][tid];
}

// ---------------- Kernel 3: masked softmax over t, per n ----------------
__global__ void k_softmax(const float* __restrict__ e_part,
                          const int* __restrict__ enc_len,
                          float* __restrict__ ali, int nparts) {
    int n = blockIdx.x;
    int len = enc_len[n];
    __shared__ float se[TI];
    __shared__ float redm[4];
    __shared__ float reds[4];
    int tid = threadIdx.x;
    int lane = tid & 63, wid = tid >> 6;

    for (int t = tid; t < TI; t += 256) {
        float s = 0.f;
        for (int p = 0; p < nparts; ++p) s += e_part[(size_t)p * M_TOT + n * TI + t];
        se[t] = s;
    }
    __syncthreads();

    float mx = -1e30f;
    for (int t = tid; t < len; t += 256) mx = fmaxf(mx, se[t]);
#pragma unroll
    for (int o = 32; o >= 1; o >>= 1) mx = fmaxf(mx, __shfl_xor(mx, o));
    if (lane == 0) redm[wid] = mx;
    __syncthreads();
    mx = fmaxf(fmaxf(redm[0], redm[1]), fmaxf(redm[2], redm[3]));

    float sm = 0.f;
    for (int t = tid; t < len; t += 256) {
        float ex = __expf(se[t] - mx);
        se[t] = ex;
        sm += ex;
    }
#pragma unroll
    for (int o = 32; o >= 1; o >>= 1) sm += __shfl_xor(sm, o);
    if (lane == 0) reds[wid] = sm;
    __syncthreads();
    float inv = 1.f / (reds[0] + reds[1] + reds[2] + reds[3]);

    for (int t = tid; t < TI; t += 256)
        ali[n * TI + t] = (t < len) ? se[t] * inv : 0.f;
}

// ---------------- Kernel 4a: ctx partials from fp16 tiled X16 ----------------
__global__ void k_ctxpart16(const _Float16* __restrict__ X16, const float* __restrict__ ali,
                            float* __restrict__ cpart) {
    int s = blockIdx.x, n = blockIdx.y;
    int tid = threadIdx.x;
    int sub = tid >> 6;            // t-phase 0..3
    int dc  = (tid & 63) * 8;      // 8 d-cols per thread
    int ktile = dc >> 6;
    int c2 = (dc & 63) * 2;
    float acc[8] = {0.f, 0.f, 0.f, 0.f, 0.f, 0.f, 0.f, 0.f};
    for (int t = s * TCHUNK + sub; t < (s + 1) * TCHUNK; t += 4) {
        int m = n * TI + t;
        int mt2 = m >> 7, r = m & 127;
        const char* p = (const char*)(X16 + (size_t)(mt2 * KT + ktile) * TILE_HALVES);
        f16x8 v = *(const f16x8*)(p + swz(r, c2));
        float a = ali[m];
#pragma unroll
        for (int j = 0; j < 8; ++j) acc[j] = fmaf(a, (float)v[j], acc[j]);
    }
    __shared__ float red[4][ED];
#pragma unroll
    for (int j = 0; j < 8; ++j) red[sub][dc + j] = acc[j];
    __syncthreads();
    if (sub == 0) {
#pragma unroll
        for (int j = 0; j < 8; ++j) {
            float sm = red[0][dc + j] + red[1][dc + j] + red[2][dc + j] + red[3][dc + j];
            cpart[((size_t)(n * NSPLIT + s)) * ED + dc + j] = sm;
        }
    }
}

// ---------------- Kernel 4b: fp32 ctx partials (fallback) ----------------
__global__ void k_ctxpart(const float* __restrict__ enc,
                          const float* __restrict__ ali,
                          float* __restrict__ cpart) {
    int s = blockIdx.x;
    int n = blockIdx.y;
    int d0 = threadIdx.x * 2;
    const float* base = enc + ((size_t)n * TI + s * TCHUNK) * ED + d0;
    const float* ap = ali + n * TI + s * TCHUNK;
    float ax = 0.f, ay = 0.f;
#pragma unroll 4
    for (int t = 0; t < TCHUNK; ++t) {
        float a = ap[t];
        float2 v = *(const float2*)(base + (size_t)t * ED);
        ax = fmaf(a, v.x, ax);
        ay = fmaf(a, v.y, ay);
    }
    float2 r; r.x = ax; r.y = ay;
    *(float2*)&cpart[((size_t)(n * NSPLIT + s)) * ED + d0] = r;
}

// ---------------- Kernel 5: reduce ctx partials ----------------
__global__ void k_ctxred(const float* __restrict__ cpart, float* __restrict__ ctx) {
    int n = blockIdx.x;
    for (int d = threadIdx.x; d < ED; d += 256) {
        float sum = 0.f;
#pragma unroll
        for (int s = 0; s < NSPLIT; ++s) sum += cpart[((size_t)(n * NSPLIT + s)) * ED + d];
        ctx[(size_t)n * ED + d] = sum;
    }
}

extern "C" void kernel_launch(void* const* d_in, const int* in_sizes, int n_in,
                              void* d_out, int out_size, void* d_ws, size_t ws_size,
                              hipStream_t stream) {
    const float* enc_pad  = (const float*)d_in[0];
    const int*   enc_len  = (const int*)d_in[1];
    const float* dec_prev = (const float*)d_in[2];
    // d_in[3] = ali_prev (unused by reference)
    const float* W_enc    = (const float*)d_in[4];
    const float* b_enc    = (const float*)d_in[5];
    const float* W_dec    = (const float*)d_in[6];
    const float* w_v      = (const float*)d_in[7];

    float* out = (float*)d_out;
    float* ali = out;              // 64000 floats
    float* ctx = out + M_TOT;      // 16384 floats

    float* ws     = (float*)d_ws;
    float* db     = ws;                          // 32*512
    float* e_part = ws + NB * AD;                // up to 4*64000
    float* cpart  = e_part + 4 * M_TOT;          // 32*20*512
    size_t fp_floats = (size_t)NB * AD + 4 * M_TOT + (size_t)NB * NSPLIT * ED;  // 600064
    _Float16* X16 = (_Float16*)((char*)d_ws + fp_floats * 4);
    _Float16* W16 = X16 + (size_t)MT * KT * TILE_HALVES;
    size_t need = fp_floats * 4 + ((size_t)MT * KT + 32) * TILE_BYTES;
    bool big = ws_size >= need;

    if (big) {
        hipLaunchKernelGGL(k_convert, dim3(MT * KT + 64), dim3(256), 0, stream,
                           enc_pad, W_enc, X16, W16, dec_prev, W_dec, b_enc, db);
        hipLaunchKernelGGL(k_score256, dim3(512), dim3(512), 0, stream,
                           X16, W16, db, w_v, e_part);
        hipLaunchKernelGGL(k_softmax, dim3(NB), dim3(256), 0, stream, e_part, enc_len, ali, 2);
        hipLaunchKernelGGL(k_ctxpart16, dim3(NSPLIT, NB), dim3(256), 0, stream, X16, ali, cpart);
    } else {
        hipLaunchKernelGGL(k_decdb, dim3(NB), dim3(256), 0, stream, dec_prev, W_dec, b_enc, db);
        hipLaunchKernelGGL(k_score_fb, dim3(M_TOT / 128, 4), dim3(256), 0, stream,
                           enc_pad, W_enc, db, w_v, e_part);
        hipLaunchKernelGGL(k_softmax, dim3(NB), dim3(256), 0, stream, e_part, enc_len, ali, 4);
        hipLaunchKernelGGL(k_ctxpart, dim3(NSPLIT, NB), dim3(256), 0, stream, enc_pad, ali, cpart);
    }
    hipLaunchKernelGGL(k_ctxred, dim3(NB), dim3(256), 0, stream, cpart, ctx);
}

// Round 8
// 131.907 us; speedup vs baseline: 1.2617x; 1.0508x over previous
//
#include <hip/hip_runtime.h>
#include <stdint.h>

// CtxAttention: additive attention (Bahdanau).
//   e[n,t]  = sum_a w_v[a] * tanh( enc_pad[n,t,:]·W_enc[a,:] + b_enc[a] + dec_prev[n,:]·W_dec[a,:] )
//   ali     = softmax_t(mask(e));  ctx[n,:] = sum_t ali[n,t] * enc_pad[n,t,:]
// Round-8: the standalone enc->fp16 convert kernel is DELETED (3 implementations all
// capped at ~2.3 TB/s / 87us). Conversion is fused into the GEMM: A staged as raw fp32
// via global_load_lds into a swizzled LDS tile (pre-swizzled global source), converted
// f32->f16 on the LDS->fragment read (VALU overlapped with MFMA). B from a 512 KB
// pre-converted W16 (k_wconvert, decdb fused). ctx reads enc fp32 (L3-warm).

#define NB  32
#define TI  2000
#define ED  512
#define AD  512
#define M_TOT (NB * TI)          // 64000
#define NSPLIT 20
#define TCHUNK (TI / NSPLIT)     // 100
#define MTS 500                  // 128-row m-tiles (score granularity)
#define NKS 16                   // K-steps of 32

using f16x8 = __attribute__((ext_vector_type(8))) _Float16;
using f32x4 = __attribute__((ext_vector_type(4))) float;

#define GLD16(g, l)                                                     \
    __builtin_amdgcn_global_load_lds(                                   \
        (const __attribute__((address_space(1))) void*)(g),             \
        (__attribute__((address_space(3))) void*)(l), 16, 0, 0)

__device__ __forceinline__ float fast_tanh(float s) {
    s = fminf(fmaxf(s, -15.f), 15.f);
    float t = __expf(2.f * s);
    return __fdividef(t - 1.f, t + 1.f);
}

__device__ __forceinline__ f16x8 cvt8(float4 a, float4 b) {
    f16x8 h;
    h[0] = (_Float16)a.x; h[1] = (_Float16)a.y; h[2] = (_Float16)a.z; h[3] = (_Float16)a.w;
    h[4] = (_Float16)b.x; h[5] = (_Float16)b.y; h[6] = (_Float16)b.z; h[7] = (_Float16)b.w;
    return h;
}

// ---------------- Kernel 0: W_enc -> W16 slabs (512 KB); + fused decdb ----------------
// W16 layout: 32 slabs of 16 KB, slab s = at2*16 + ks; within slab: row r (0..255) of
// 64 B = f16 k-cols [ks*32, ks*32+32) of W_enc row a = at2*256 + r.  Linear, no swizzle
// (row stride 64 B is bank-optimal for the GEMM's bF reads).
// bx in [0,128): convert; [128,160): decdb row n = bx-128.
__global__ void k_wconvert(const float* __restrict__ Wenc, _Float16* __restrict__ W16,
                           const float* __restrict__ dec_prev, const float* __restrict__ W_dec,
                           const float* __restrict__ b_enc, float* __restrict__ db) {
    __shared__ float xd[ED];
    int bx = blockIdx.x;
    int tid = threadIdx.x;
    if (bx >= 128) {
        int n = bx - 128;
        for (int k = tid; k < ED; k += 256) xd[k] = dec_prev[n * ED + k];
        __syncthreads();
        for (int a = tid; a < AD; a += 256) {
            const float* wr = W_dec + (size_t)a * ED;
            float s = 0.f;
#pragma unroll 8
            for (int k = 0; k < ED; k += 4) {
                float4 w = *(const float4*)(wr + k);
                s += xd[k] * w.x + xd[k + 1] * w.y + xd[k + 2] * w.z + xd[k + 3] * w.w;
            }
            db[n * AD + a] = s + b_enc[a];
        }
        return;
    }
    int idx  = bx * 4096 + tid * 16;   // byte offset into W16 (512 KB total)
    int slab = idx >> 14;              // 0..31
    int o    = idx & 16383;
    int r    = o >> 6;                 // 0..255
    int q    = o & 63;                 // byte within row
    int a    = (slab >> 4) * 256 + r;
    int k    = (slab & 15) * 32 + (q >> 1);
    const float* s = Wenc + (size_t)a * ED + k;
    float4 x0 = *(const float4*)s;
    float4 x1 = *(const float4*)(s + 4);
    *(f16x8*)((char*)W16 + idx) = cvt8(x0, x1);
}

// ---------------- standalone decdb (fallback path only) ----------------
__global__ void k_decdb(const float* __restrict__ dec_prev,
                        const float* __restrict__ W_dec,
                        const float* __restrict__ b_enc,
                        float* __restrict__ db) {
    int n = blockIdx.x;
    __shared__ float xd[ED];
    for (int k = threadIdx.x; k < ED; k += 256) xd[k] = dec_prev[n * ED + k];
    __syncthreads();
    for (int a = threadIdx.x; a < AD; a += 256) {
        const float* wr = W_dec + (size_t)a * ED;
        float s = 0.f;
#pragma unroll 8
        for (int k = 0; k < ED; k += 4) {
            float4 w = *(const float4*)(wr + k);
            s += xd[k] * w.x + xd[k + 1] * w.y + xd[k + 2] * w.z + xd[k + 3] * w.w;
        }
        db[n * AD + a] = s + b_enc[a];
    }
}

// ---------------- Kernel 2: fused score GEMM, 128x256 tile, 4 waves, fp32-A-in-LDS ----------
// grid 1008: fid -> g=fid>>4, r=fid&15, at2=r>>3, mt=g*8+(r&7).  at2=0/1 of one mt are
// 8 apart in fid -> same XCD (round-robin) -> enc fp32 L2 reuse on the twin read.
// As: 128 rows x 32 fp32, physical byte = (row*128 + c) ^ ((row&7)<<4)  (XOR swizzle;
// staged via GLD16 with the INVERSE-swizzled global source -> both-sides rule).
// aF fragment read: 2x ds_read_b128 fp32 + v_cvt_pkrtz to f16 (overlaps MFMA).
__launch_bounds__(256, 2)
__global__ void k_score256(const float* __restrict__ enc, const _Float16* __restrict__ W16,
                           const float* __restrict__ db, const float* __restrict__ wv,
                           float* __restrict__ e_part) {
    __shared__ alignas(16) char As[16384];   // 128 x 32 fp32, swizzled
    __shared__ alignas(16) char Bs[16384];   // 256 x 32 f16, linear (64 B rows)

    int fid = blockIdx.x;
    int g = fid >> 4, r = fid & 15;
    int at2 = r >> 3;
    int mt  = g * 8 + (r & 7);
    if (mt >= MTS) return;

    const int tid  = threadIdx.x;
    const int lane = tid & 63;
    const int wn   = (tid >> 6) & 3;   // wave N-quarter: cols wn*64..+64
    const int m0   = mt * 128;
    const int a0   = at2 * 256;
    const int lr   = lane & 15;
    const int gk   = lane >> 4;        // k-group 0..3

    const char* wbase = (const char*)W16 + ((size_t)(at2 * 16) << 14);

    // staging constants: thread stages 4x16B of A and 4x16B of B per K-step
    const int sr0 = tid >> 3;          // A row base (0..31), +32 per round
    const int sq  = (tid & 7) * 16;    // byte col within 128B A row

    f32x4 acc[8][4];
#pragma unroll
    for (int rb = 0; rb < 8; ++rb)
#pragma unroll
        for (int cb = 0; cb < 4; ++cb) acc[rb][cb] = (f32x4){0.f, 0.f, 0.f, 0.f};

    for (int ks = 0; ks < NKS; ++ks) {
        // ---- stage A (fp32, pre-swizzled source) + B (f16 slab, linear) ----
#pragma unroll
        for (int i = 0; i < 4; ++i) {
            int rr = i * 32 + sr0;
            const float* gsrc = enc + (size_t)(m0 + rr) * ED + ks * 32
                                + ((sq ^ ((rr & 7) << 4)) >> 2);
            GLD16(gsrc, As + i * 4096 + tid * 16);
        }
        {
            const char* wsl = wbase + (ks << 14);
#pragma unroll
            for (int j = 0; j < 4; ++j)
                GLD16(wsl + j * 4096 + tid * 16, Bs + j * 4096 + tid * 16);
        }
        __syncthreads();   // drains vmcnt -> tiles visible

        // ---- compute: convert A frags on read, 32 MFMA ----
        {
            f16x8 aF[8], bF[4];
#pragma unroll
            for (int rb = 0; rb < 8; ++rb) {
                int row  = rb * 16 + lr;
                int base = row * 128 + gk * 32;
                int sw   = (row & 7) << 4;
                f32x4 lo = *(const f32x4*)(As + (base ^ sw));
                f32x4 hi = *(const f32x4*)(As + ((base + 16) ^ sw));
                f16x8 h;
                h[0] = (_Float16)lo[0]; h[1] = (_Float16)lo[1];
                h[2] = (_Float16)lo[2]; h[3] = (_Float16)lo[3];
                h[4] = (_Float16)hi[0]; h[5] = (_Float16)hi[1];
                h[6] = (_Float16)hi[2]; h[7] = (_Float16)hi[3];
                aF[rb] = h;
            }
#pragma unroll
            for (int cb = 0; cb < 4; ++cb) {
                int brow = wn * 64 + cb * 16 + lr;
                bF[cb] = *(const f16x8*)(Bs + brow * 64 + gk * 16);
            }
            __builtin_amdgcn_s_setprio(1);
#pragma unroll
            for (int rb = 0; rb < 8; ++rb)
#pragma unroll
                for (int cb = 0; cb < 4; ++cb)
                    acc[rb][cb] = __builtin_amdgcn_mfma_f32_16x16x32_f16(
                        aF[rb], bF[cb], acc[rb][cb], 0, 0, 0);
            __builtin_amdgcn_s_setprio(0);
        }
        __syncthreads();   // everyone done reading before next stage overwrites
    }

    // epilogue: rs = sum over 64 cols of w_v*tanh(acc+db); shfl-reduce 16 lanes;
    // cross-wave (4 N-quarters) reduce via e_red overlaid on As (idle now).
    float* e_red = (float*)As;   // [4][128]
    float wvv[4];
#pragma unroll
    for (int cb = 0; cb < 4; ++cb) wvv[cb] = wv[a0 + wn * 64 + cb * 16 + lr];

#pragma unroll
    for (int rb = 0; rb < 8; ++rb) {
#pragma unroll
        for (int i = 0; i < 4; ++i) {
            int row_local = rb * 16 + gk * 4 + i;   // C/D: row=(lane>>4)*4+reg
            int m = m0 + row_local;
            int n = m / TI;
            const float* dbp = db + (size_t)n * AD + a0 + wn * 64;
            float rs = 0.f;
#pragma unroll
            for (int cb = 0; cb < 4; ++cb) {
                float s = acc[rb][cb][i] + dbp[cb * 16 + lr];  // col = lane&15
                rs += fast_tanh(s) * wvv[cb];
            }
            rs += __shfl_xor(rs, 1);
            rs += __shfl_xor(rs, 2);
            rs += __shfl_xor(rs, 4);
            rs += __shfl_xor(rs, 8);
            if (lr == 0) e_red[wn * 128 + row_local] = rs;
        }
    }
    __syncthreads();
    if (tid < 128)
        e_part[(size_t)at2 * M_TOT + m0 + tid] =
            e_red[tid] + e_red[128 + tid] + e_red[256 + tid] + e_red[384 + tid];
}

// ---------------- fallback fp32 GEMM (convert-in-kernel) if ws too small ----------------
__launch_bounds__(256, 2)
__global__ void k_score_fb(const float* __restrict__ X, const float* __restrict__ W,
                           const float* __restrict__ db, const float* __restrict__ wv,
                           float* __restrict__ e_part) {
    __shared__ alignas(16) _Float16 Xs[128][72];
    __shared__ alignas(16) _Float16 Ws[128][72];
    __shared__ float e_red[2][128];

    const int tid = threadIdx.x, lane = tid & 63, wid = tid >> 6;
    const int wr = wid >> 1, wc = wid & 1;
    const int m0 = blockIdx.x * 128, a0 = blockIdx.y * 128;

    f32x4 acc[4][4];
#pragma unroll
    for (int rb = 0; rb < 4; ++rb)
#pragma unroll
        for (int cb = 0; cb < 4; ++cb) acc[rb][cb] = (f32x4){0.f, 0.f, 0.f, 0.f};

    const int lr = lane & 15;
    const int lk = (lane >> 4) << 3;

    for (int kt = 0; kt < ED; kt += 64) {
#pragma unroll
        for (int i = 0; i < 4; ++i) {
            int idx = tid + i * 256, r = idx >> 3, c = (idx & 7) << 3;
            const float* gx = X + (size_t)(m0 + r) * ED + kt + c;
            float4 x0 = *(const float4*)gx, x1 = *(const float4*)(gx + 4);
            *(f16x8*)&Xs[r][c] = cvt8(x0, x1);
            const float* gw = W + (size_t)(a0 + r) * ED + kt + c;
            float4 w0 = *(const float4*)gw, w1 = *(const float4*)(gw + 4);
            *(f16x8*)&Ws[r][c] = cvt8(w0, w1);
        }
        __syncthreads();
#pragma unroll
        for (int kb = 0; kb < 64; kb += 32) {
            f16x8 aF[4], bF[4];
#pragma unroll
            for (int rb = 0; rb < 4; ++rb) aF[rb] = *(const f16x8*)&Xs[wr * 64 + rb * 16 + lr][kb + lk];
#pragma unroll
            for (int cb = 0; cb < 4; ++cb) bF[cb] = *(const f16x8*)&Ws[wc * 64 + cb * 16 + lr][kb + lk];
#pragma unroll
            for (int rb = 0; rb < 4; ++rb)
#pragma unroll
                for (int cb = 0; cb < 4; ++cb)
                    acc[rb][cb] = __builtin_amdgcn_mfma_f32_16x16x32_f16(aF[rb], bF[cb], acc[rb][cb], 0, 0, 0);
        }
        __syncthreads();
    }

    const int lg = lane >> 4;
    float wvv[4];
#pragma unroll
    for (int cb = 0; cb < 4; ++cb) wvv[cb] = wv[a0 + wc * 64 + cb * 16 + lr];
#pragma unroll
    for (int rb = 0; rb < 4; ++rb) {
#pragma unroll
        for (int i = 0; i < 4; ++i) {
            int row_local = wr * 64 + rb * 16 + lg * 4 + i;
            int m = m0 + row_local;
            int n = m / TI;
            const float* dbp = db + (size_t)n * AD + a0 + wc * 64;
            float rs = 0.f;
#pragma unroll
            for (int cb = 0; cb < 4; ++cb) {
                float s = acc[rb][cb][i] + dbp[cb * 16 + lr];
                rs += fast_tanh(s) * wvv[cb];
            }
            rs += __shfl_xor(rs, 1);
            rs += __shfl_xor(rs, 2);
            rs += __shfl_xor(rs, 4);
            rs += __shfl_xor(rs, 8);
            if (lr == 0) e_red[wc][row_local] = rs;
        }
    }
    __syncthreads();
    if (tid < 128)
        e_part[(size_t)blockIdx.y * M_TOT + m0 + tid] = e_red[0][tid] + e_red[1][tid];
}

// ---------------- Kernel 3: masked softmax over t, per n ----------------
__global__ void k_softmax(const float* __restrict__ e_part,
                          const int* __restrict__ enc_len,
                          float* __restrict__ ali, int nparts) {
    int n = blockIdx.x;
    int len = enc_len[n];
    __shared__ float se[TI];
    __shared__ float redm[4];
    __shared__ float reds[4];
    int tid = threadIdx.x;
    int lane = tid & 63, wid = tid >> 6;

    for (int t = tid; t < TI; t += 256) {
        float s = 0.f;
        for (int p = 0; p < nparts; ++p) s += e_part[(size_t)p * M_TOT + n * TI + t];
        se[t] = s;
    }
    __syncthreads();

    float mx = -1e30f;
    for (int t = tid; t < len; t += 256) mx = fmaxf(mx, se[t]);
#pragma unroll
    for (int o = 32; o >= 1; o >>= 1) mx = fmaxf(mx, __shfl_xor(mx, o));
    if (lane == 0) redm[wid] = mx;
    __syncthreads();
    mx = fmaxf(fmaxf(redm[0], redm[1]), fmaxf(redm[2], redm[3]));

    float sm = 0.f;
    for (int t = tid; t < len; t += 256) {
        float ex = __expf(se[t] - mx);
        se[t] = ex;
        sm += ex;
    }
#pragma unroll
    for (int o = 32; o >= 1; o >>= 1) sm += __shfl_xor(sm, o);
    if (lane == 0) reds[wid] = sm;
    __syncthreads();
    float inv = 1.f / (reds[0] + reds[1] + reds[2] + reds[3]);

    for (int t = tid; t < TI; t += 256)
        ali[n * TI + t] = (t < len) ? se[t] * inv : 0.f;
}

// ---------------- Kernel 4: ctx partials over t-chunks (fp32 enc, L3-warm) ----------------
__global__ void k_ctxpart(const float* __restrict__ enc,
                          const float* __restrict__ ali,
                          float* __restrict__ cpart) {
    int s = blockIdx.x;   // 0..NSPLIT-1
    int n = blockIdx.y;   // 0..31
    int d0 = threadIdx.x * 2;
    const float* base = enc + ((size_t)n * TI + s * TCHUNK) * ED + d0;
    const float* ap = ali + n * TI + s * TCHUNK;
    float ax = 0.f, ay = 0.f;
#pragma unroll 4
    for (int t = 0; t < TCHUNK; ++t) {
        float a = ap[t];
        float2 v = *(const float2*)(base + (size_t)t * ED);
        ax = fmaf(a, v.x, ax);
        ay = fmaf(a, v.y, ay);
    }
    float2 r; r.x = ax; r.y = ay;
    *(float2*)&cpart[((size_t)(n * NSPLIT + s)) * ED + d0] = r;
}

// ---------------- Kernel 5: reduce ctx partials ----------------
__global__ void k_ctxred(const float* __restrict__ cpart, float* __restrict__ ctx) {
    int n = blockIdx.x;
    for (int d = threadIdx.x; d < ED; d += 256) {
        float sum = 0.f;
#pragma unroll
        for (int s = 0; s < NSPLIT; ++s) sum += cpart[((size_t)(n * NSPLIT + s)) * ED + d];
        ctx[(size_t)n * ED + d] = sum;
    }
}

extern "C" void kernel_launch(void* const* d_in, const int* in_sizes, int n_in,
                              void* d_out, int out_size, void* d_ws, size_t ws_size,
                              hipStream_t stream) {
    const float* enc_pad  = (const float*)d_in[0];
    const int*   enc_len  = (const int*)d_in[1];
    const float* dec_prev = (const float*)d_in[2];
    // d_in[3] = ali_prev (unused by reference)
    const float* W_enc    = (const float*)d_in[4];
    const float* b_enc    = (const float*)d_in[5];
    const float* W_dec    = (const float*)d_in[6];
    const float* w_v      = (const float*)d_in[7];

    float* out = (float*)d_out;
    float* ali = out;              // 64000 floats
    float* ctx = out + M_TOT;      // 16384 floats

    float* ws     = (float*)d_ws;
    float* db     = ws;                          // 32*512
    float* e_part = ws + NB * AD;                // up to 4*64000
    float* cpart  = e_part + 4 * M_TOT;          // 32*20*512
    size_t fp_floats = (size_t)NB * AD + 4 * M_TOT + (size_t)NB * NSPLIT * ED;  // 600064
    _Float16* W16 = (_Float16*)((char*)d_ws + fp_floats * 4);
    size_t need = fp_floats * 4 + (size_t)512 * 1024;   // ~2.9 MB
    bool big = ws_size >= need;

    if (big) {
        hipLaunchKernelGGL(k_wconvert, dim3(160), dim3(256), 0, stream,
                           W_enc, W16, dec_prev, W_dec, b_enc, db);
        hipLaunchKernelGGL(k_score256, dim3(1008), dim3(256), 0, stream,
                           enc_pad, W16, db, w_v, e_part);
        hipLaunchKernelGGL(k_softmax, dim3(NB), dim3(256), 0, stream, e_part, enc_len, ali, 2);
    } else {
        hipLaunchKernelGGL(k_decdb, dim3(NB), dim3(256), 0, stream, dec_prev, W_dec, b_enc, db);
        hipLaunchKernelGGL(k_score_fb, dim3(M_TOT / 128, 4), dim3(256), 0, stream,
                           enc_pad, W_enc, db, w_v, e_part);
        hipLaunchKernelGGL(k_softmax, dim3(NB), dim3(256), 0, stream, e_part, enc_len, ali, 4);
    }
    hipLaunchKernelGGL(k_ctxpart, dim3(NSPLIT, NB), dim3(256), 0, stream, enc_pad, ali, cpart);
    hipLaunchKernelGGL(k_ctxred, dim3(NB), dim3(256), 0, stream, cpart, ctx);
}

// Round 9
// 119.914 us; speedup vs baseline: 1.3879x; 1.1000x over previous
//
#include <hip/hip_runtime.h>
#include <stdint.h>

// CtxAttention: additive attention (Bahdanau).
//   e[n,t]  = sum_a w_v[a] * tanh( enc_pad[n,t,:]·W_enc[a,:] + b_enc[a] + dec_prev[n,:]·W_dec[a,:] )
//   ali     = softmax_t(mask(e));  ctx[n,:] = sum_t ali[n,t] * enc_pad[n,t,:]
// Round-9 k_score256: 128x512 tile (full A-dim -> enc read ONCE, complete e rows),
// 8 waves (2Mx4N), BK=32 double-buffered (stage k+1 before compute k -> latency hidden),
// A fp32 in swizzled LDS (2-way-free, verified bank math) + cvt-on-read,
// B k-major panels in LDS (16B/row-frag -> conflict-free, no XOR needed; round-8's
// 64B-row layout was an 8-way conflict = 5.12M SQ_LDS_BANK_CONFLICT).

#define NB  32
#define TI  2000
#define ED  512
#define AD  512
#define M_TOT (NB * TI)          // 64000
#define NSPLIT 20
#define TCHUNK (TI / NSPLIT)     // 100
#define MTS 500                  // 128-row m-tiles
#define NKS 16                   // K-steps of 32

using f16x8 = __attribute__((ext_vector_type(8))) _Float16;
using f32x4 = __attribute__((ext_vector_type(4))) float;

#define GLD16(g, l)                                                     \
    __builtin_amdgcn_global_load_lds(                                   \
        (const __attribute__((address_space(1))) void*)(g),             \
        (__attribute__((address_space(3))) void*)(l), 16, 0, 0)

__device__ __forceinline__ float fast_tanh(float s) {
    s = fminf(fmaxf(s, -15.f), 15.f);
    float t = __expf(2.f * s);
    return __fdividef(t - 1.f, t + 1.f);
}

__device__ __forceinline__ f16x8 cvt8(float4 a, float4 b) {
    f16x8 h;
    h[0] = (_Float16)a.x; h[1] = (_Float16)a.y; h[2] = (_Float16)a.z; h[3] = (_Float16)a.w;
    h[4] = (_Float16)b.x; h[5] = (_Float16)b.y; h[6] = (_Float16)b.z; h[7] = (_Float16)b.w;
    return h;
}

// ---------------- Kernel 0: W_enc -> W16 (512 KB, k-major panels); + fused decdb ----------
// W16: 16 slabs (ks) of 32 KB; slab = 4 panels (gk) of 8 KB; panel: a (0..511) x 16 B
// holding f16 W_enc[a][ks*32+gk*8 .. +8].  GEMM stages a slab linearly; the bF read
// (16 consecutive rows x 16 B) is bank-conflict-free by construction.
// bx in [0,128): convert; [128,160): decdb row n = bx-128.
__global__ void k_wconvert(const float* __restrict__ Wenc, _Float16* __restrict__ W16,
                           const float* __restrict__ dec_prev, const float* __restrict__ W_dec,
                           const float* __restrict__ b_enc, float* __restrict__ db) {
    __shared__ float xd[ED];
    int bx = blockIdx.x;
    int tid = threadIdx.x;
    if (bx >= 128) {
        int n = bx - 128;
        for (int k = tid; k < ED; k += 256) xd[k] = dec_prev[n * ED + k];
        __syncthreads();
        for (int a = tid; a < AD; a += 256) {
            const float* wr = W_dec + (size_t)a * ED;
            float s = 0.f;
#pragma unroll 8
            for (int k = 0; k < ED; k += 4) {
                float4 w = *(const float4*)(wr + k);
                s += xd[k] * w.x + xd[k + 1] * w.y + xd[k + 2] * w.z + xd[k + 3] * w.w;
            }
            db[n * AD + a] = s + b_enc[a];
        }
        return;
    }
    int idx = bx * 4096 + tid * 16;    // physical byte in W16 (512 KB)
    int ks  = idx >> 15;               // slab 0..15
    int r   = idx & 32767;
    int gk  = r >> 13;                 // panel 0..3
    int a   = (r & 8191) >> 4;         // row 0..511
    int k   = ks * 32 + gk * 8;
    const float* s = Wenc + (size_t)a * ED + k;
    float4 x0 = *(const float4*)s;
    float4 x1 = *(const float4*)(s + 4);
    *(f16x8*)((char*)W16 + idx) = cvt8(x0, x1);
}

// ---------------- standalone decdb (fallback path only) ----------------
__global__ void k_decdb(const float* __restrict__ dec_prev,
                        const float* __restrict__ W_dec,
                        const float* __restrict__ b_enc,
                        float* __restrict__ db) {
    int n = blockIdx.x;
    __shared__ float xd[ED];
    for (int k = threadIdx.x; k < ED; k += 256) xd[k] = dec_prev[n * ED + k];
    __syncthreads();
    for (int a = threadIdx.x; a < AD; a += 256) {
        const float* wr = W_dec + (size_t)a * ED;
        float s = 0.f;
#pragma unroll 8
        for (int k = 0; k < ED; k += 4) {
            float4 w = *(const float4*)(wr + k);
            s += xd[k] * w.x + xd[k + 1] * w.y + xd[k + 2] * w.z + xd[k + 3] * w.w;
        }
        db[n * AD + a] = s + b_enc[a];
    }
}

// ---------------- Kernel 2: fused score GEMM, 128x512 tile, 8 waves, dbuf BK=32 ----------
__launch_bounds__(512, 2)
__global__ void k_score256(const float* __restrict__ enc, const _Float16* __restrict__ W16,
                           const float* __restrict__ db, const float* __restrict__ wv,
                           float* __restrict__ e_out) {
    __shared__ alignas(16) char As0[16384];   // 128 x 32 fp32, 128B rows, XOR-swizzled
    __shared__ alignas(16) char As1[16384];
    __shared__ alignas(16) char Bs0[32768];   // 4 k-panels x (512 x 16B f16), linear
    __shared__ alignas(16) char Bs1[32768];

    const int mt   = blockIdx.x;
    const int tid  = threadIdx.x;
    const int lane = tid & 63;
    const int w    = tid >> 6;        // wave 0..7
    const int wm   = w >> 2;          // M-half: rows wm*64..+64
    const int wn   = w & 3;           // N-quarter: cols wn*128..+128
    const int m0   = mt * 128;
    const int lr   = lane & 15;
    const int gk   = lane >> 4;       // k-group 0..3

    // A staging geometry: thread covers rows {srow, srow+64}, 16B col sq (pre-swizzled src)
    const int srow = tid >> 3;                       // 0..63
    const int sq   = (tid & 7) * 16;                 // byte col in 128B row
    const int sqx  = (sq ^ ((srow & 7) << 4)) >> 2;  // float offset, inverse-swizzled
    const float* asrc = enc + (size_t)(m0 + srow) * ED + sqx;

    const char* wbase = (const char*)W16;

    f32x4 acc[4][8];
#pragma unroll
    for (int rb = 0; rb < 4; ++rb)
#pragma unroll
        for (int cb = 0; cb < 8; ++cb) acc[rb][cb] = (f32x4){0.f, 0.f, 0.f, 0.f};

#define STAGE(ks, dA, dB)                                               \
    {                                                                   \
        GLD16(asrc + (ks) * 32,            (dA) + tid * 16);            \
        GLD16(asrc + 64 * ED + (ks) * 32,  (dA) + 8192 + tid * 16);     \
        const char* wsl = wbase + ((ks) << 15);                         \
        GLD16(wsl + tid * 16,          (dB) + tid * 16);                \
        GLD16(wsl + 8192 + tid * 16,   (dB) + 8192 + tid * 16);         \
        GLD16(wsl + 16384 + tid * 16,  (dB) + 16384 + tid * 16);        \
        GLD16(wsl + 24576 + tid * 16,  (dB) + 24576 + tid * 16);        \
    }

#define COMPUTE(sA, sB)                                                          \
    {                                                                            \
        f16x8 aF[4], bF[8];                                                      \
        _Pragma("unroll")                                                        \
        for (int rb = 0; rb < 4; ++rb) {                                         \
            int row = wm * 64 + rb * 16 + lr;                                    \
            int b0  = row * 128 + gk * 32;                                       \
            int sw  = (row & 7) << 4;                                            \
            f32x4 lo = *(const f32x4*)((sA) + (b0 ^ sw));                        \
            f32x4 hi = *(const f32x4*)((sA) + ((b0 + 16) ^ sw));                 \
            f16x8 h;                                                             \
            h[0] = (_Float16)lo[0]; h[1] = (_Float16)lo[1];                      \
            h[2] = (_Float16)lo[2]; h[3] = (_Float16)lo[3];                      \
            h[4] = (_Float16)hi[0]; h[5] = (_Float16)hi[1];                      \
            h[6] = (_Float16)hi[2]; h[7] = (_Float16)hi[3];                      \
            aF[rb] = h;                                                          \
        }                                                                        \
        _Pragma("unroll")                                                        \
        for (int cb = 0; cb < 8; ++cb) {                                         \
            int brow = wn * 128 + cb * 16 + lr;                                  \
            bF[cb] = *(const f16x8*)((sB) + gk * 8192 + brow * 16);              \
        }                                                                        \
        __builtin_amdgcn_s_setprio(1);                                           \
        _Pragma("unroll")                                                        \
        for (int rb = 0; rb < 4; ++rb)                                           \
            _Pragma("unroll")                                                    \
            for (int cb = 0; cb < 8; ++cb)                                       \
                acc[rb][cb] = __builtin_amdgcn_mfma_f32_16x16x32_f16(            \
                    aF[rb], bF[cb], acc[rb][cb], 0, 0, 0);                       \
        __builtin_amdgcn_s_setprio(0);                                           \
    }

#define ITER(k, Ac, Bc, An, Bn)  STAGE(k + 1, An, Bn); COMPUTE(Ac, Bc); __syncthreads();

    STAGE(0, As0, Bs0); __syncthreads();
    ITER(0,  As0, Bs0, As1, Bs1)
    ITER(1,  As1, Bs1, As0, Bs0)
    ITER(2,  As0, Bs0, As1, Bs1)
    ITER(3,  As1, Bs1, As0, Bs0)
    ITER(4,  As0, Bs0, As1, Bs1)
    ITER(5,  As1, Bs1, As0, Bs0)
    ITER(6,  As0, Bs0, As1, Bs1)
    ITER(7,  As1, Bs1, As0, Bs0)
    ITER(8,  As0, Bs0, As1, Bs1)
    ITER(9,  As1, Bs1, As0, Bs0)
    ITER(10, As0, Bs0, As1, Bs1)
    ITER(11, As1, Bs1, As0, Bs0)
    ITER(12, As0, Bs0, As1, Bs1)
    ITER(13, As1, Bs1, As0, Bs0)
    ITER(14, As0, Bs0, As1, Bs1)
    COMPUTE(As1, Bs1); __syncthreads();
#undef ITER
#undef COMPUTE
#undef STAGE

    // epilogue: rs = sum over this wave's 128 cols of w_v*tanh(acc+db); shfl-reduce the
    // 16 col-lanes; cross-wave (4 wn quarters) reduce via e_red overlaid on As0.
    float* e_red = (float*)As0;   // [4][128]
    float wvv[8];
#pragma unroll
    for (int cb = 0; cb < 8; ++cb) wvv[cb] = wv[wn * 128 + cb * 16 + lr];

#pragma unroll
    for (int rb = 0; rb < 4; ++rb) {
#pragma unroll
        for (int i = 0; i < 4; ++i) {
            int row_local = wm * 64 + rb * 16 + gk * 4 + i;   // C/D: row=(lane>>4)*4+reg
            int m = m0 + row_local;
            int n = m / TI;
            const float* dbp = db + (size_t)n * AD + wn * 128;
            float rs = 0.f;
#pragma unroll
            for (int cb = 0; cb < 8; ++cb) {
                float s = acc[rb][cb][i] + dbp[cb * 16 + lr];  // col = lane&15
                rs += fast_tanh(s) * wvv[cb];
            }
            rs += __shfl_xor(rs, 1);
            rs += __shfl_xor(rs, 2);
            rs += __shfl_xor(rs, 4);
            rs += __shfl_xor(rs, 8);
            if (lr == 0) e_red[wn * 128 + row_local] = rs;
        }
    }
    __syncthreads();
    if (tid < 128)
        e_out[m0 + tid] =
            e_red[tid] + e_red[128 + tid] + e_red[256 + tid] + e_red[384 + tid];
}

// ---------------- fallback fp32 GEMM (convert-in-kernel) if ws too small ----------------
__launch_bounds__(256, 2)
__global__ void k_score_fb(const float* __restrict__ X, const float* __restrict__ W,
                           const float* __restrict__ db, const float* __restrict__ wv,
                           float* __restrict__ e_part) {
    __shared__ alignas(16) _Float16 Xs[128][72];
    __shared__ alignas(16) _Float16 Ws[128][72];
    __shared__ float e_red[2][128];

    const int tid = threadIdx.x, lane = tid & 63, wid = tid >> 6;
    const int wr = wid >> 1, wc = wid & 1;
    const int m0 = blockIdx.x * 128, a0 = blockIdx.y * 128;

    f32x4 acc[4][4];
#pragma unroll
    for (int rb = 0; rb < 4; ++rb)
#pragma unroll
        for (int cb = 0; cb < 4; ++cb) acc[rb][cb] = (f32x4){0.f, 0.f, 0.f, 0.f};

    const int lr = lane & 15;
    const int lk = (lane >> 4) << 3;

    for (int kt = 0; kt < ED; kt += 64) {
#pragma unroll
        for (int i = 0; i < 4; ++i) {
            int idx = tid + i * 256, r = idx >> 3, c = (idx & 7) << 3;
            const float* gx = X + (size_t)(m0 + r) * ED + kt + c;
            float4 x0 = *(const float4*)gx, x1 = *(const float4*)(gx + 4);
            *(f16x8*)&Xs[r][c] = cvt8(x0, x1);
            const float* gw = W + (size_t)(a0 + r) * ED + kt + c;
            float4 w0 = *(const float4*)gw, w1 = *(const float4*)(gw + 4);
            *(f16x8*)&Ws[r][c] = cvt8(w0, w1);
        }
        __syncthreads();
#pragma unroll
        for (int kb = 0; kb < 64; kb += 32) {
            f16x8 aF[4], bF[4];
#pragma unroll
            for (int rb = 0; rb < 4; ++rb) aF[rb] = *(const f16x8*)&Xs[wr * 64 + rb * 16 + lr][kb + lk];
#pragma unroll
            for (int cb = 0; cb < 4; ++cb) bF[cb] = *(const f16x8*)&Ws[wc * 64 + cb * 16 + lr][kb + lk];
#pragma unroll
            for (int rb = 0; rb < 4; ++rb)
#pragma unroll
                for (int cb = 0; cb < 4; ++cb)
                    acc[rb][cb] = __builtin_amdgcn_mfma_f32_16x16x32_f16(aF[rb], bF[cb], acc[rb][cb], 0, 0, 0);
        }
        __syncthreads();
    }

    const int lg = lane >> 4;
    float wvv[4];
#pragma unroll
    for (int cb = 0; cb < 4; ++cb) wvv[cb] = wv[a0 + wc * 64 + cb * 16 + lr];
#pragma unroll
    for (int rb = 0; rb < 4; ++rb) {
#pragma unroll
        for (int i = 0; i < 4; ++i) {
            int row_local = wr * 64 + rb * 16 + lg * 4 + i;
            int m = m0 + row_local;
            int n = m / TI;
            const float* dbp = db + (size_t)n * AD + a0 + wc * 64;
            float rs = 0.f;
#pragma unroll
            for (int cb = 0; cb < 4; ++cb) {
                float s = acc[rb][cb][i] + dbp[cb * 16 + lr];
                rs += fast_tanh(s) * wvv[cb];
            }
            rs += __shfl_xor(rs, 1);
            rs += __shfl_xor(rs, 2);
            rs += __shfl_xor(rs, 4);
            rs += __shfl_xor(rs, 8);
            if (lr == 0) e_red[wc][row_local] = rs;
        }
    }
    __syncthreads();
    if (tid < 128)
        e_part[(size_t)blockIdx.y * M_TOT + m0 + tid] = e_red[0][tid] + e_red[1][tid];
}

// ---------------- Kernel 3: masked softmax over t, per n ----------------
__global__ void k_softmax(const float* __restrict__ e_part,
                          const int* __restrict__ enc_len,
                          float* __restrict__ ali, int nparts) {
    int n = blockIdx.x;
    int len = enc_len[n];
    __shared__ float se[TI];
    __shared__ float redm[4];
    __shared__ float reds[4];
    int tid = threadIdx.x;
    int lane = tid & 63, wid = tid >> 6;

    for (int t = tid; t < TI; t += 256) {
        float s = 0.f;
        for (int p = 0; p < nparts; ++p) s += e_part[(size_t)p * M_TOT + n * TI + t];
        se[t] = s;
    }
    __syncthreads();

    float mx = -1e30f;
    for (int t = tid; t < len; t += 256) mx = fmaxf(mx, se[t]);
#pragma unroll
    for (int o = 32; o >= 1; o >>= 1) mx = fmaxf(mx, __shfl_xor(mx, o));
    if (lane == 0) redm[wid] = mx;
    __syncthreads();
    mx = fmaxf(fmaxf(redm[0], redm[1]), fmaxf(redm[2], redm[3]));

    float sm = 0.f;
    for (int t = tid; t < len; t += 256) {
        float ex = __expf(se[t] - mx);
        se[t] = ex;
        sm += ex;
    }
#pragma unroll
    for (int o = 32; o >= 1; o >>= 1) sm += __shfl_xor(sm, o);
    if (lane == 0) reds[wid] = sm;
    __syncthreads();
    float inv = 1.f / (reds[0] + reds[1] + reds[2] + reds[3]);

    for (int t = tid; t < TI; t += 256)
        ali[n * TI + t] = (t < len) ? se[t] * inv : 0.f;
}

// ---------------- Kernel 4: ctx partials over t-chunks (fp32 enc, L3-warm) ----------------
__global__ void k_ctxpart(const float* __restrict__ enc,
                          const float* __restrict__ ali,
                          float* __restrict__ cpart) {
    int s = blockIdx.x;   // 0..NSPLIT-1
    int n = blockIdx.y;   // 0..31
    int d0 = threadIdx.x * 2;
    const float* base = enc + ((size_t)n * TI + s * TCHUNK) * ED + d0;
    const float* ap = ali + n * TI + s * TCHUNK;
    float ax = 0.f, ay = 0.f;
#pragma unroll 4
    for (int t = 0; t < TCHUNK; ++t) {
        float a = ap[t];
        float2 v = *(const float2*)(base + (size_t)t * ED);
        ax = fmaf(a, v.x, ax);
        ay = fmaf(a, v.y, ay);
    }
    float2 r; r.x = ax; r.y = ay;
    *(float2*)&cpart[((size_t)(n * NSPLIT + s)) * ED + d0] = r;
}

// ---------------- Kernel 5: reduce ctx partials ----------------
__global__ void k_ctxred(const float* __restrict__ cpart, float* __restrict__ ctx) {
    int n = blockIdx.x;
    for (int d = threadIdx.x; d < ED; d += 256) {
        float sum = 0.f;
#pragma unroll
        for (int s = 0; s < NSPLIT; ++s) sum += cpart[((size_t)(n * NSPLIT + s)) * ED + d];
        ctx[(size_t)n * ED + d] = sum;
    }
}

extern "C" void kernel_launch(void* const* d_in, const int* in_sizes, int n_in,
                              void* d_out, int out_size, void* d_ws, size_t ws_size,
                              hipStream_t stream) {
    const float* enc_pad  = (const float*)d_in[0];
    const int*   enc_len  = (const int*)d_in[1];
    const float* dec_prev = (const float*)d_in[2];
    // d_in[3] = ali_prev (unused by reference)
    const float* W_enc    = (const float*)d_in[4];
    const float* b_enc    = (const float*)d_in[5];
    const float* W_dec    = (const float*)d_in[6];
    const float* w_v      = (const float*)d_in[7];

    float* out = (float*)d_out;
    float* ali = out;              // 64000 floats
    float* ctx = out + M_TOT;      // 16384 floats

    float* ws     = (float*)d_ws;
    float* db     = ws;                          // 32*512
    float* e_part = ws + NB * AD;                // up to 4*64000 (main path uses 1)
    float* cpart  = e_part + 4 * M_TOT;          // 32*20*512
    size_t fp_floats = (size_t)NB * AD + 4 * M_TOT + (size_t)NB * NSPLIT * ED;  // 600064
    _Float16* W16 = (_Float16*)((char*)d_ws + fp_floats * 4);
    size_t need = fp_floats * 4 + (size_t)512 * 1024;   // ~2.9 MB
    bool big = ws_size >= need;

    if (big) {
        hipLaunchKernelGGL(k_wconvert, dim3(160), dim3(256), 0, stream,
                           W_enc, W16, dec_prev, W_dec, b_enc, db);
        hipLaunchKernelGGL(k_score256, dim3(MTS), dim3(512), 0, stream,
                           enc_pad, W16, db, w_v, e_part);
        hipLaunchKernelGGL(k_softmax, dim3(NB), dim3(256), 0, stream, e_part, enc_len, ali, 1);
    } else {
        hipLaunchKernelGGL(k_decdb, dim3(NB), dim3(256), 0, stream, dec_prev, W_dec, b_enc, db);
        hipLaunchKernelGGL(k_score_fb, dim3(M_TOT / 128, 4), dim3(256), 0, stream,
                           enc_pad, W_enc, db, w_v, e_part);
        hipLaunchKernelGGL(k_softmax, dim3(NB), dim3(256), 0, stream, e_part, enc_len, ali, 4);
    }
    hipLaunchKernelGGL(k_ctxpart, dim3(NSPLIT, NB), dim3(256), 0, stream, enc_pad, ali, cpart);
    hipLaunchKernelGGL(k_ctxred, dim3(NB), dim3(256), 0, stream, cpart, ctx);
}